// Round 9
// baseline (273.944 us; speedup 1.0000x reference)
//
#include <hip/hip_runtime.h>
#include <hip/hip_cooperative_groups.h>

namespace cg = cooperative_groups;

typedef unsigned short u16;

constexpr int kN   = 512;
constexpr int kIN  = 256;
constexpr int kHID = 256;
constexpr int kHD  = 64;
constexpr int kOUT = 256;

// ---------- bf16 helpers ----------
__device__ __forceinline__ float us2f(u16 u){
  union { unsigned int i; float f; } c; c.i = ((unsigned int)u) << 16; return c.f;
}
__device__ __forceinline__ u16 f2us(float f){
  union { float f; unsigned int i; } c; c.f = f;
  unsigned int r = c.i + 0x7fff + ((c.i >> 16) & 1);
  return (u16)(r >> 16);
}
__device__ __forceinline__ float ldraw(const void* p, size_t i, bool f32){
  return f32 ? ((const float*)p)[i] : us2f(((const u16*)p)[i]);
}

// ---------- per-block dtype probe (reads first 16KB of V) ----------
__device__ bool probe_is_f32(const unsigned int* __restrict__ V){
  __shared__ int cnt;
  if (threadIdx.x == 0) cnt = 0;
  __syncthreads();
  int c = 0;
  for (int k = threadIdx.x; k < 4096; k += 256){
    float x = us2f((u16)(V[k] & 0xffffu));
    if (!(fabsf(x) <= 32.0f)) c++;
  }
  atomicAdd(&cnt, c);
  __syncthreads();
  return cnt > 64;
}

// ---------- block reduction (256 threads) ----------
__device__ __forceinline__ float blk_red(float v, float* tmp, bool isMax){
  int lane = threadIdx.x & 63, wv = threadIdx.x >> 6;
  #pragma unroll
  for (int o = 32; o > 0; o >>= 1){
    float t = __shfl_down(v, o, 64);
    v = isMax ? fmaxf(v, t) : (v + t);
  }
  __syncthreads();
  if (lane == 0) tmp[wv] = v;
  __syncthreads();
  float r = tmp[0];
  for (int i = 1; i < 4; ++i) r = isMax ? fmaxf(r, tmp[i]) : (r + tmp[i]);
  return r;
}

struct ConvArgs { const void* src[23]; float* dst[23]; int n[23]; };
struct GSeg2 { const float* X; const float* W; float* C; int ldx, ldw, ldc, K; };
struct GS32 { const float* X; const float* W; float* C; int ldx, ldw, ldc, K; int bkn; };

struct MegaArgs {
  const unsigned int* Vraw;
  const int* adj;
  int* flag; void* out;
  const void *rca0,*rca1,*rcw2,*rcb2,*rtw2,*rpw2;   // raw small weights (S0 reads)
  float *Vf,*prevf,*W1f,*sa1f,*cw1f,*cb1f,*cw2f,*cb2f,*ca0f,*ca1f;
  float *tw1f,*tb1f,*tw2f,*tb2f,*pw1f,*pb1f,*pw2f,*pb2f;
  float *W2f,*opwf,*opbf,*lngf,*lnbf;
  float *tw2t,*pw2t,*Wcomb,*OM,*ow4;
  float *Wh1,*e1v,*wadj,*Hc,*Am,*Bm,*uvec,*beta;
  float *s2,*maxp,*zp,*MZ,*gsum;
  float *htp0,*htp1,*hpp0,*hpp1,*hpp2,*hidden_t,*hidden_p;
  float *tfm,*cfm,*H4v,*Xp,*out3;
  ConvArgs ca;
  GSeg2 gs[8];
};

// ================== GEMM-32 body: 32x32 tile, BK=32, 2x2 micro, dbuf ==================
__device__ __forceinline__ void gemm32_body(const GS32 sg, int tm, int tn, int tid,
                                            float* Xs, float* Ws)
{
  const int i0 = tm << 5, n0 = tn << 5;
  const int xrow = tid >> 3;
  const int xk = (tid & 7) << 2;
  const int rg = (tid >> 4) << 1;
  const int cg = (tid & 15) << 1;
  const float* Xb = sg.X + (size_t)i0 * sg.ldx;
  const float* Wb = sg.bkn ? (sg.W + n0) : (sg.W + (size_t)n0 * sg.ldw);
  float4 xr, wr;
  auto loadT = [&](int kt){
    xr = *(const float4*)(Xb + (size_t)xrow * sg.ldx + kt + xk);
    if (sg.bkn) wr = *(const float4*)(Wb + (size_t)(kt + xrow) * sg.ldw + xk);
    else        wr = *(const float4*)(Wb + (size_t)xrow * sg.ldw + kt + xk);
  };
  auto writeT = [&](int bu){
    float* xs = Xs + bu*1152;
    xs[(xk+0)*36 + xrow] = xr.x; xs[(xk+1)*36 + xrow] = xr.y;
    xs[(xk+2)*36 + xrow] = xr.z; xs[(xk+3)*36 + xrow] = xr.w;
    float* wsp = Ws + bu*1152;
    if (sg.bkn){
      wsp[xrow*36 + xk+0] = wr.x; wsp[xrow*36 + xk+1] = wr.y;
      wsp[xrow*36 + xk+2] = wr.z; wsp[xrow*36 + xk+3] = wr.w;
    } else {
      wsp[(xk+0)*36 + xrow] = wr.x; wsp[(xk+1)*36 + xrow] = wr.y;
      wsp[(xk+2)*36 + xrow] = wr.z; wsp[(xk+3)*36 + xrow] = wr.w;
    }
  };
  loadT(0); writeT(0); __syncthreads();
  float a00=0,a01=0,a10=0,a11=0;
  const int nkt = sg.K >> 5;
  for (int t = 0; t < nkt; ++t){
    if (t+1 < nkt) loadT((t+1) << 5);
    const float* xs = Xs + (t&1)*1152;
    const float* wsp = Ws + (t&1)*1152;
    #pragma unroll
    for (int kk = 0; kk < 32; ++kk){
      float2 av = *(const float2*)&xs[kk*36 + rg];
      float2 bv = *(const float2*)&wsp[kk*36 + cg];
      a00 += av.x*bv.x; a01 += av.x*bv.y;
      a10 += av.y*bv.x; a11 += av.y*bv.y;
    }
    if (t+1 < nkt) writeT((t+1)&1);
    __syncthreads();
  }
  float* cp = sg.C + (size_t)(i0+rg)*sg.ldc + n0 + cg;
  *(float2*)cp = make_float2(a00, a01);
  *(float2*)(cp + sg.ldc) = make_float2(a10, a11);
}

// ================== stage bodies ==================

// ---- S0: [0,256) convert | [256,768) packsel | 768 ub+zeroH4v | 769,770 transposes ----
__device__ void body_s0(const MegaArgs& A, int it, int tid, bool f32, char* SM)
{
  if (it < 256){
    if (it == 0){
      if (tid == 0) *A.flag = f32 ? 1 : 0;
      A.e1v[tid] = 0.f; A.e1v[tid + 256] = 0.f;
    }
    int t = it*256 + tid;
    for (int s = 0; s < 23; ++s){
      int n4 = A.ca.n[s] >> 2;
      float4* d = (float4*)A.ca.dst[s];
      if (f32){
        const float4* sf = (const float4*)A.ca.src[s];
        for (int i = t; i < n4; i += 65536) d[i] = sf[i];
      } else {
        const ushort4* sb = (const ushort4*)A.ca.src[s];
        for (int i = t; i < n4; i += 65536){
          ushort4 u = sb[i];
          d[i] = make_float4(us2f(u.x), us2f(u.y), us2f(u.z), us2f(u.w));
        }
      }
    }
  } else if (it < 768){
    unsigned long long* msk = (unsigned long long*)SM;
    int* sj = (int*)(SM + 64);
    int i = it - 256;
    int w = tid >> 6, lane = tid & 63;
    unsigned long long m0 = __ballot(A.adj[(size_t)i*kN + tid] != 0);
    unsigned long long m1 = __ballot(A.adj[(size_t)i*kN + 256 + tid] != 0);
    if (lane == 0){ msk[w] = m0; msk[4 + w] = m1; }
    __syncthreads();
    if (tid == 0){
      int j0 = -1, j1 = -1;
      for (int c = 0; c < 8 && j1 < 0; ++c){
        unsigned long long m = msk[c];
        while (m && j1 < 0){
          int bb = __builtin_ctzll(m);
          int j = c*64 + bb;
          if (j0 < 0) j0 = j; else j1 = j;
          m &= m - 1;
        }
      }
      if (j1 < 0) j0 = -1;
      sj[0] = j0; sj[1] = j1;
    }
    __syncthreads();
    int j0 = sj[0], j1 = sj[1];
    A.Xp[(size_t)i*768 + tid]       = ldraw(A.Vraw, (size_t)i*kIN + tid, f32);
    A.Xp[(size_t)i*768 + 256 + tid] = (j0 >= 0) ? ldraw(A.Vraw, (size_t)j0*kIN + tid, f32) : 0.f;
    A.Xp[(size_t)i*768 + 512 + tid] = (j1 >= 0) ? ldraw(A.Vraw, (size_t)j1*kIN + tid, f32) : 0.f;
  } else if (it == 768){
    float* st = (float*)SM;
    if (tid < 64){ st[tid] = ldraw(A.rca0, tid, f32) + ldraw(A.rca1, tid, f32); A.H4v[tid] = 0.f; }
    __syncthreads();
    float a = 0.f;
    for (int d = 0; d < kHD; ++d) a += ldraw(A.rcw2, (size_t)d*kHID + tid, f32) * st[d];
    A.uvec[tid] = a;
    if (tid == 0){
      float b = 0.f;
      for (int d = 0; d < kHD; ++d) b += ldraw(A.rcb2, d, f32) * st[d];
      *A.beta = b;
    }
  } else {
    const void* src = (it == 769) ? A.rtw2 : A.rpw2;
    float* dst = (it == 769) ? A.tw2t : A.pw2t;
    float* st = (float*)SM;   // 64*65 floats
    for (int ch = 0; ch < 4; ++ch){
      __syncthreads();
      #pragma unroll
      for (int e = 0; e < 16; ++e){
        int lin = e*256 + tid, r = lin >> 6, c = lin & 63;
        st[r*65 + c] = ldraw(src, (size_t)r*256 + ch*64 + c, f32);
      }
      __syncthreads();
      #pragma unroll
      for (int e = 0; e < 16; ++e){
        int lin = e*256 + tid, kc = lin >> 6, dd = lin & 63;
        dst[(size_t)(ch*64 + kc)*64 + dd] = st[dd*65 + kc];
      }
    }
  }
}

// ---- S1: [0,256) gemmA(+e1) | [256,336) Wcomb | [336,352) OM | 352 ow4 ----
__device__ void body_gemmA(const MegaArgs& A, int it, int tid, char* SM)
{
  float (*Xs)[32][68] = (float (*)[32][68])SM;
  float (*Ws)[32][68] = (float (*)[32][68])(SM + 17408);
  int seg = it >> 5, x = it & 31;
  const GSeg2 sg = A.gs[seg];
  const int tm = x & 7, tn = x >> 3;
  const int i0 = tm << 6, n0 = tn << 6;

  const int xrow = tid >> 3;
  const int xk   = (tid & 7) << 2;
  const int rg = (tid >> 4) << 2;
  const int cg = (tid & 15) << 2;

  const float* Xb = sg.X + (size_t)i0 * sg.ldx;
  const float* Wb = sg.W + (size_t)n0 * sg.ldw;

  float4 xr0, xr1, wr0, wr1;
  auto loadT = [&](int kt){
    xr0 = *(const float4*)(Xb + (size_t)xrow * sg.ldx + kt + xk);
    xr1 = *(const float4*)(Xb + (size_t)(xrow+32) * sg.ldx + kt + xk);
    wr0 = *(const float4*)(Wb + (size_t)xrow * sg.ldw + kt + xk);
    wr1 = *(const float4*)(Wb + (size_t)(xrow+32) * sg.ldw + kt + xk);
  };
  auto writeT = [&](int bu){
    Xs[bu][xk+0][xrow] = xr0.x;  Xs[bu][xk+1][xrow] = xr0.y;
    Xs[bu][xk+2][xrow] = xr0.z;  Xs[bu][xk+3][xrow] = xr0.w;
    Xs[bu][xk+0][xrow+32] = xr1.x;  Xs[bu][xk+1][xrow+32] = xr1.y;
    Xs[bu][xk+2][xrow+32] = xr1.z;  Xs[bu][xk+3][xrow+32] = xr1.w;
    Ws[bu][xk+0][xrow]    = wr0.x; Ws[bu][xk+1][xrow]    = wr0.y;
    Ws[bu][xk+2][xrow]    = wr0.z; Ws[bu][xk+3][xrow]    = wr0.w;
    Ws[bu][xk+0][xrow+32] = wr1.x; Ws[bu][xk+1][xrow+32] = wr1.y;
    Ws[bu][xk+2][xrow+32] = wr1.z; Ws[bu][xk+3][xrow+32] = wr1.w;
  };

  loadT(0); writeT(0); __syncthreads();

  float acc[4][4] = {};
  const int nkt = sg.K >> 5;
  for (int t = 0; t < nkt; ++t){
    if (t + 1 < nkt) loadT((t + 1) << 5);
    const int bu = t & 1;
    #pragma unroll
    for (int kk = 0; kk < 32; ++kk){
      const float4 av = *(const float4*)&Xs[bu][kk][rg];
      const float4 bv = *(const float4*)&Ws[bu][kk][cg];
      acc[0][0]+=av.x*bv.x; acc[0][1]+=av.x*bv.y; acc[0][2]+=av.x*bv.z; acc[0][3]+=av.x*bv.w;
      acc[1][0]+=av.y*bv.x; acc[1][1]+=av.y*bv.y; acc[1][2]+=av.y*bv.z; acc[1][3]+=av.y*bv.w;
      acc[2][0]+=av.z*bv.x; acc[2][1]+=av.z*bv.y; acc[2][2]+=av.z*bv.z; acc[2][3]+=av.z*bv.w;
      acc[3][0]+=av.w*bv.x; acc[3][1]+=av.w*bv.y; acc[3][2]+=av.w*bv.z; acc[3][3]+=av.w*bv.w;
    }
    if (t + 1 < nkt) writeT((t + 1) & 1);
    __syncthreads();
  }

  #pragma unroll
  for (int ri = 0; ri < 4; ++ri)
    *(float4*)(sg.C + (size_t)(i0 + rg + ri) * sg.ldc + (n0 + cg)) =
      make_float4(acc[ri][0], acc[ri][1], acc[ri][2], acc[ri][3]);

  if (seg == 0){
    int cb = n0 + cg;
    float s0 = A.sa1f[cb], s1 = A.sa1f[cb+1], s2v = A.sa1f[cb+2], s3 = A.sa1f[cb+3];
    #pragma unroll
    for (int ri = 0; ri < 4; ++ri){
      float v = acc[ri][0]*s0 + acc[ri][1]*s1 + acc[ri][2]*s2v + acc[ri][3]*s3;
      v += __shfl_xor(v, 1, 16);
      v += __shfl_xor(v, 2, 16);
      v += __shfl_xor(v, 4, 16);
      v += __shfl_xor(v, 8, 16);
      if ((tid & 15) == 0) atomicAdd(&A.e1v[i0 + rg + ri], v);
    }
  }
}

__device__ void body_s1(const MegaArgs& A, int it, int tid, char* SM)
{
  if (it < 256){
    body_gemmA(A, it, tid, SM);
  } else if (it < 336){
    int q = it - 256, tm = q & 7, tn = q >> 3;
    const float* Wsrc = A.W2f + ((tn < 8) ? 0 : 64);
    GS32 sg{A.opwf, Wsrc, A.Wcomb, 256, 385, 320, 256, 1};
    gemm32_body(sg, tm, tn, tid, (float*)SM, (float*)(SM + 9216));
  } else if (it < 352){
    int q = it - 336;
    GS32 sg{A.opwf, A.W2f + 256, A.OM, 256, 385, 64, 256, 1};
    gemm32_body(sg, q & 7, q >> 3, tid, (float*)SM, (float*)(SM + 9216));
  } else {
    float* st = (float*)SM;
    st[tid] = A.W2f[(size_t)tid*385 + 384];
    __syncthreads();
    float a = 0.f;
    const float* orow = A.opwf + (size_t)tid*256;
    for (int m = 0; m < 256; m += 4){
      float4 o4 = *(const float4*)(orow + m);
      a += o4.x*st[m] + o4.y*st[m+1] + o4.z*st[m+2] + o4.w*st[m+3];
    }
    A.ow4[tid] = a;
  }
}

// ---- S2: [0,128) redH | [128,640) h1stats+wadj ----
__device__ void body_s2(const MegaArgs& A, int it, int tid, char* SM)
{
  if (it < 128){
    int f = it*256 + tid;
    int c4 = f & 63;
    {
      float4 a = ((const float4*)A.htp0)[f], bb = ((const float4*)A.htp1)[f];
      float4 bi = ((const float4*)A.tb1f)[c4];
      ((float4*)A.hidden_t)[f] = make_float4(
        fmaxf(a.x+bb.x+bi.x,0.f), fmaxf(a.y+bb.y+bi.y,0.f),
        fmaxf(a.z+bb.z+bi.z,0.f), fmaxf(a.w+bb.w+bi.w,0.f));
    }
    {
      float4 a = ((const float4*)A.hpp0)[f], bb = ((const float4*)A.hpp1)[f];
      float4 c = ((const float4*)A.hpp2)[f];
      float4 bi = ((const float4*)A.pb1f)[c4];
      ((float4*)A.hidden_p)[f] = make_float4(
        fmaxf(a.x+bb.x+c.x+bi.x,0.f), fmaxf(a.y+bb.y+c.y+bi.y,0.f),
        fmaxf(a.z+bb.z+c.z+bi.z,0.f), fmaxf(a.w+bb.w+c.w+bi.w,0.f));
    }
  } else {
    float* st = (float*)SM;
    int i = it - 128;
    int m0 = A.adj[(size_t)i*kN + tid];
    int m1 = A.adj[(size_t)i*kN + tid + 256];
    float ea = A.e1v[tid], eb = A.e1v[tid+256];
    float v0 = m0 ? ea : -1e30f;
    float v1 = m1 ? eb : -1e30f;
    float m = blk_red(fmaxf(v0, v1), st, true);
    float z = blk_red((m0 ? expf(ea-m) : 0.f) + (m1 ? expf(eb-m) : 0.f), st, false);
    float iz = 1.0f / z;
    A.wadj[(size_t)i*kN + tid]       = m0 ? expf(ea - m) * iz : 0.f;
    A.wadj[(size_t)i*kN + tid + 256] = m1 ? expf(eb - m) * iz : 0.f;
  }
}

// ---- S3: [0,64) gemmB(reg) | [64,1088) s2 | [1088,1216) H1gemm->Hc ----
__device__ void body_s3(const MegaArgs& A, int it, int tid, char* SM)
{
  if (it < 64){
    int m = it >> 5, grp = it & 31;
    const float* X  = m ? A.hidden_p : A.hidden_t;
    const float* Wt = m ? A.pw2t : A.tw2t;
    const float* bi = m ? A.pb2f : A.tb2f;
    float* C = m ? A.cfm : A.tfm;
    int i0 = grp*16 + (tid >> 6)*4;
    int d = tid & 63;
    const float* x0 = X + (size_t)i0*256;
    const float* x1 = x0 + 256;
    const float* x2 = x0 + 512;
    const float* x3 = x0 + 768;
    float a0=0.f, a1=0.f, a2=0.f, a3=0.f;
    for (int k = 0; k < 256; k += 4){
      float w0 = Wt[(size_t)(k+0)*64 + d];
      float w1 = Wt[(size_t)(k+1)*64 + d];
      float w2 = Wt[(size_t)(k+2)*64 + d];
      float w3 = Wt[(size_t)(k+3)*64 + d];
      float4 f0 = *(const float4*)(x0 + k);
      float4 f1 = *(const float4*)(x1 + k);
      float4 f2 = *(const float4*)(x2 + k);
      float4 f3 = *(const float4*)(x3 + k);
      a0 += f0.x*w0 + f0.y*w1 + f0.z*w2 + f0.w*w3;
      a1 += f1.x*w0 + f1.y*w1 + f1.z*w2 + f1.w*w3;
      a2 += f2.x*w0 + f2.y*w1 + f2.z*w2 + f2.w*w3;
      a3 += f3.x*w0 + f3.y*w1 + f3.z*w2 + f3.w*w3;
    }
    float bd = bi[d];
    C[(size_t)(i0+0)*64 + d] = a0 + bd;
    C[(size_t)(i0+1)*64 + d] = a1 + bd;
    C[(size_t)(i0+2)*64 + d] = a2 + bd;
    C[(size_t)(i0+3)*64 + d] = a3 + bd;
  } else if (it < 1088){
    float* aib = (float*)SM;            // [4][256]
    float* uu  = aib + 1024;            // [256]
    int q = it - 64;
    int i0 = (q & 127) * 4, j0 = (q >> 7) * 64;
    int wv = tid >> 6, lane = tid & 63;
    uu[tid] = A.uvec[tid];
    float b1v = A.cb1f[tid];
    #pragma unroll
    for (int r = 0; r < 4; ++r) aib[r*256 + tid] = A.Am[(size_t)(i0+r)*kHID + tid] + b1v;
    __syncthreads();
    int i = i0 + wv, j = j0 + lane;
    const float4* bp = (const float4*)(A.Bm + (size_t)j*kHID);
    float acc = *A.beta;
    #pragma unroll 8
    for (int k4 = 0; k4 < kHID/4; ++k4){
      float4 bv = bp[k4];
      float4 a4 = *(const float4*)&aib[wv*256 + k4*4];
      float4 u4 = *(const float4*)&uu[k4*4];
      acc += fmaxf(a4.x+bv.x,0.f)*u4.x + fmaxf(a4.y+bv.y,0.f)*u4.y
           + fmaxf(a4.z+bv.z,0.f)*u4.z + fmaxf(a4.w+bv.w,0.f)*u4.w;
    }
    if (j == i) acc = -1e30f;
    A.s2[(size_t)i*kN + j] = acc;
    float m = acc;
    #pragma unroll
    for (int o = 32; o > 0; o >>= 1) m = fmaxf(m, __shfl_down(m, o, 64));
    m = __shfl(m, 0, 64);
    float e = expf(acc - m);
    #pragma unroll
    for (int o = 32; o > 0; o >>= 1) e += __shfl_down(e, o, 64);
    if (lane == 0){
      int pb = q*4 + wv;
      A.maxp[pb] = m; A.zp[pb] = e;
    }
  } else {
    int bb = it - 1088;
    GS32 sg{A.wadj, A.Wh1, A.Hc, 512, 256, 320, 512, 1};
    gemm32_body(sg, bb & 15, bb >> 4, tid, (float*)SM, (float*)(SM + 9216));
  }
}

// ---- S4: [0,64) h3->Hc | [64,72) h4 | 72 mz+zero gsum ----
__device__ void body_s4(const MegaArgs& A, int it, int tid, char* SM)
{
  if (it < 64){
    int d = it;
    int lane = tid & 63, wv = tid >> 6;
    float v0 = A.tfm[(size_t)(2*tid)*kHD + d];
    float v1 = A.tfm[(size_t)(2*tid+1)*kHD + d];
    float s = v0 + v1;
    float x = s;
    #pragma unroll
    for (int off = 1; off < 64; off <<= 1){
      float y = __shfl_up(x, off, 64);
      if (lane >= off) x += y;
    }
    float* wsum = (float*)SM;
    if (lane == 63) wsum[wv] = x;
    __syncthreads();
    float base = 0.f;
    for (int k = 0; k < wv; ++k) base += wsum[k];
    float excl = base + x - s;
    A.Hc[(size_t)(2*tid)*320 + 256 + d]   = (excl + v0) / (float)(2*tid + 1);
    A.Hc[(size_t)(2*tid+1)*320 + 256 + d] = (excl + s)  / (float)(2*tid + 2);
  } else if (it < 72){
    float* sm = (float*)SM;
    int d = tid & 63, sub = tid >> 6;
    int r0 = (it-64)*64 + sub*16;
    float s = 0.f;
    #pragma unroll
    for (int e = 0; e < 16; ++e) s += A.cfm[(size_t)(r0+e)*kHD + d];
    sm[sub*64 + d] = s;
    __syncthreads();
    if (tid < 64)
      atomicAdd(&A.H4v[tid], sm[tid] + sm[64+tid] + sm[128+tid] + sm[192+tid]);
  } else {
    float* red = (float*)SM;
    float m = -1e30f;
    #pragma unroll
    for (int r = 0; r < 16; ++r) m = fmaxf(m, A.maxp[tid + 256*r]);
    m = blk_red(m, red, true);
    float z = 0.f;
    #pragma unroll
    for (int r = 0; r < 16; ++r) z += A.zp[tid + 256*r] * expf(A.maxp[tid + 256*r] - m);
    z = blk_red(z, red, false);
    if (tid == 0){ A.MZ[0] = m; A.MZ[1] = z; }
    A.gsum[tid] = 0.f;
  }
}

// ---- S5: [0,1024) gpart | [1024,1152) out3 (Hc @ Wcomb^T) ----
__device__ void body_s5(const MegaArgs& A, int it, int tid, char* SM)
{
  if (it < 1024){
    float* wt = (float*)SM;             // [16][16]
    int i0 = (it & 31) * 16, j0 = (it >> 5) * 16;
    float M = A.MZ[0], invZ = 1.0f / A.MZ[1];
    {
      int r = tid >> 4, c = tid & 15;
      wt[r*16 + c] = expf(A.s2[(size_t)(i0+r)*kN + (j0+c)] - M) * invZ;
    }
    float b1v = A.cb1f[tid];
    float aib[16];
    #pragma unroll
    for (int r = 0; r < 16; ++r) aib[r] = A.Am[(size_t)(i0+r)*kHID + tid] + b1v;
    __syncthreads();
    float acc = 0.f;
    for (int j = 0; j < 16; ++j){
      float bj = A.Bm[(size_t)(j0+j)*kHID + tid];
      #pragma unroll
      for (int r = 0; r < 16; ++r)
        acc += wt[r*16 + j] * fmaxf(aib[r] + bj, 0.f);
    }
    atomicAdd(&A.gsum[tid], acc);
  } else {
    int q = it - 1024;
    GS32 sg{A.Hc, A.Wcomb, A.out3, 320, 320, 256, 320, 0};
    gemm32_body(sg, q & 15, q >> 4, tid, (float*)SM, (float*)(SM + 9216));
  }
}

// ---- S6: final ----
__device__ void body_s6(const MegaArgs& A, int it, int tid, bool f32, char* SM)
{
  float* gs   = (float*)SM;             // 256
  float* part = gs + 256;               // 256 ([64][4])
  float* h2s  = part + 256;             // 64
  float* cc2s = h2s + 64;               // 256
  gs[tid] = A.gsum[tid];
  __syncthreads();
  {
    int dd = tid >> 2, q = tid & 3;
    float a = 0.f;
    for (int kk = 0; kk < 64; ++kk){
      int k = q*64 + kk;
      a += gs[k] * A.cw2f[(size_t)dd*kHID + k];
    }
    part[dd*4 + q] = a;
  }
  __syncthreads();
  if (tid < kHD)
    h2s[tid] = A.cb2f[tid] + part[tid*4] + part[tid*4+1] + part[tid*4+2] + part[tid*4+3];
  __syncthreads();
  {
    float a = 0.f;
    const float* om = A.OM + (size_t)tid*64;
    for (int d = 0; d < kHD; d += 4){
      float4 o4 = *(const float4*)(om + d);
      a += o4.x*h2s[d] + o4.y*h2s[d+1] + o4.z*h2s[d+2] + o4.w*h2s[d+3];
    }
    cc2s[tid] = a;
  }
  __syncthreads();
  int row = it*4 + (tid >> 6), lane = tid & 63;
  float h4r = (row < kHD) ? A.H4v[row] : 0.f;
  float4 v  = *(const float4*)(A.out3 + (size_t)row*kOUT + lane*4);
  float4 c2 = *(const float4*)(&cc2s[lane*4]);
  float4 o4 = *(const float4*)(A.ow4 + lane*4);
  float4 pb = *(const float4*)(A.opbf + lane*4);
  v.x += c2.x + h4r*o4.x + pb.x;
  v.y += c2.y + h4r*o4.y + pb.y;
  v.z += c2.z + h4r*o4.z + pb.z;
  v.w += c2.w + h4r*o4.w + pb.w;
  float s = v.x + v.y + v.z + v.w;
  #pragma unroll
  for (int o = 32; o > 0; o >>= 1) s += __shfl_xor(s, o, 64);
  float mu = s * (1.0f/kOUT);
  float dx = v.x-mu, dy = v.y-mu, dz = v.z-mu, dw = v.w-mu;
  float ss = dx*dx + dy*dy + dz*dz + dw*dw;
  #pragma unroll
  for (int o = 32; o > 0; o >>= 1) ss += __shfl_xor(ss, o, 64);
  float rs = rsqrtf(ss * (1.0f/kOUT) + 1e-5f);
  float4 g  = *(const float4*)(A.lngf + lane*4);
  float4 be = *(const float4*)(A.lnbf + lane*4);
  float y0 = dx*rs*g.x + be.x, y1 = dy*rs*g.y + be.y;
  float y2 = dz*rs*g.z + be.z, y3 = dw*rs*g.w + be.w;
  y0 = (y0 > 0.f) ? y0 : expm1f(y0);
  y1 = (y1 > 0.f) ? y1 : expm1f(y1);
  y2 = (y2 > 0.f) ? y2 : expm1f(y2);
  y3 = (y3 > 0.f) ? y3 : expm1f(y3);
  if (f32){
    *(float4*)((float*)A.out + (size_t)row*kOUT + lane*4) = make_float4(y0,y1,y2,y3);
  } else {
    ushort4 u; u.x = f2us(y0); u.y = f2us(y1); u.z = f2us(y2); u.w = f2us(y3);
    ((ushort4*)A.out)[(size_t)row*64 + lane] = u;
  }
}

// ================== stage runner ==================
__device__ __forceinline__ int stage_count(int s){
  switch(s){
    case 0: return 771;  case 1: return 353;  case 2: return 640;
    case 3: return 1216; case 4: return 73;   case 5: return 1152;
    default: return 128;
  }
}

__device__ void run_stage(int s, const MegaArgs& A, bool f32, char* SM, int b0, int nb)
{
  const int n = stage_count(s);
  const int tid = threadIdx.x;
  for (int it = b0; it < n; it += nb){
    switch(s){
      case 0: body_s0(A, it, tid, f32, SM); break;
      case 1: body_s1(A, it, tid, SM); break;
      case 2: body_s2(A, it, tid, SM); break;
      case 3: body_s3(A, it, tid, SM); break;
      case 4: body_s4(A, it, tid, SM); break;
      case 5: body_s5(A, it, tid, SM); break;
      default: body_s6(A, it, tid, f32, SM); break;
    }
    __syncthreads();
  }
}

// ================== cooperative mega-kernel ==================
__global__ __launch_bounds__(256) void k_mega(MegaArgs A)
{
  __shared__ __align__(16) char SM[34816];
  cg::grid_group grid = cg::this_grid();
  bool f32 = probe_is_f32(A.Vraw);
  #pragma unroll 1
  for (int s = 0; s < 7; ++s){
    run_stage(s, A, f32, SM, blockIdx.x, gridDim.x);
    if (s < 6){ __threadfence(); grid.sync(); }
  }
}

// ================== fallback per-stage kernels ==================
constexpr int kStageSM[7] = {16896, 34816, 64, 18432, 1024, 18432, 3328};

template<int S>
__global__ __launch_bounds__(256) void k_stage_one(MegaArgs A)
{
  __shared__ __align__(16) char SM[kStageSM[S]];
  bool f32 = (S == 0) ? probe_is_f32(A.Vraw) : (*A.flag != 0);
  run_stage(S, A, f32, SM, blockIdx.x, gridDim.x);
}

extern "C" void kernel_launch(void* const* d_in, const int* in_sizes, int n_in,
                              void* d_out, int out_size, void* d_ws, size_t ws_size,
                              hipStream_t stream)
{
  const void* V     = d_in[0];
  const int*  adj   = (const int*)d_in[1];
  const void* prev  = d_in[2];
  const void* W1    = d_in[3];
  // d_in[4] = sa0 : dead (row-shift invariant softmax)
  const void* sa1   = d_in[5];
  const void* ce_w1 = d_in[6];
  const void* ce_b1 = d_in[7];
  const void* ce_w2 = d_in[8];
  const void* ce_b2 = d_in[9];
  const void* ca0   = d_in[10];
  const void* ca1   = d_in[11];
  const void* te_w1 = d_in[12];
  const void* te_b1 = d_in[13];
  const void* te_w2 = d_in[14];
  const void* te_b2 = d_in[15];
  // d_in[16,17] = ta0,ta1 : dead
  const void* pe_w1 = d_in[18];
  const void* pe_b1 = d_in[19];
  const void* pe_w2 = d_in[20];
  const void* pe_b2 = d_in[21];
  // d_in[22,23] = pa0,pa1 : dead
  const void* W2    = d_in[24];
  const void* op_w  = d_in[25];
  const void* op_b  = d_in[26];
  const void* ln_g  = d_in[27];
  const void* ln_b  = d_in[28];

  // ---- workspace layout (floats) ----
  float* ws  = (float*)d_ws;
  int*  flag = (int*)ws;               // 16 floats reserved
  float* p   = ws + 16;
  float* Vf   = p; p += 131072;
  float* prevf= p; p += 131072;
  float* W1f  = p; p += 65536;
  float* sa1f = p; p += 256;
  float* cw1f = p; p += 131072;
  float* cb1f = p; p += 256;
  float* cw2f = p; p += 16384;
  float* cb2f = p; p += 64;
  float* ca0f = p; p += 64;
  float* ca1f = p; p += 64;
  float* tw1f = p; p += 131072;
  float* tb1f = p; p += 256;
  float* tw2f = p; p += 16384;
  float* tb2f = p; p += 64;
  float* pw1f = p; p += 196608;
  float* pb1f = p; p += 256;
  float* pw2f = p; p += 16384;
  float* pb2f = p; p += 64;
  float* W2f  = p; p += 98560;
  float* opwf = p; p += 65536;
  float* opbf = p; p += 256;
  float* lngf = p; p += 256;
  float* lnbf = p; p += 256;
  float* tw2t = p; p += 16384;
  float* pw2t = p; p += 16384;
  float* Wcomb= p; p += 81920;
  float* OM   = p; p += 16384;
  float* ow4  = p; p += 256;
  float* Wh1      = p; p += 131072;
  float* e1v      = p; p += 512;
  float* wadj     = p; p += 262144;
  float* Hc       = p; p += 163840;
  float* Am       = p; p += 131072;
  float* Bm       = p; p += 131072;
  float* uvec     = p; p += 256;
  float* beta     = p; p += 16;
  float* s2       = p; p += 262144;
  float* maxp     = p; p += 4096;
  float* zpart    = p; p += 4096;
  float* MZ       = p; p += 16;
  float* gsum     = p; p += 256;
  float* htp0     = p; p += 131072;
  float* htp1     = p; p += 131072;
  float* hpp0     = p; p += 131072;
  float* hpp1     = p; p += 131072;
  float* hpp2     = p; p += 131072;
  float* hidden_t = p; p += 131072;
  float* hidden_p = p; p += 131072;
  float* tfm      = p; p += 32768;
  float* cfm      = p; p += 32768;
  float* H4v      = p; p += 64;
  float* Xp       = p; p += 393216;
  float* out3     = p; p += 131072;

  // ---- args bundle ----
  MegaArgs A;
  A.Vraw = (const unsigned int*)V; A.adj = adj; A.flag = flag; A.out = d_out;
  A.rca0 = ca0; A.rca1 = ca1; A.rcw2 = ce_w2; A.rcb2 = ce_b2; A.rtw2 = te_w2; A.rpw2 = pe_w2;
  A.Vf=Vf; A.prevf=prevf; A.W1f=W1f; A.sa1f=sa1f; A.cw1f=cw1f; A.cb1f=cb1f;
  A.cw2f=cw2f; A.cb2f=cb2f; A.ca0f=ca0f; A.ca1f=ca1f;
  A.tw1f=tw1f; A.tb1f=tb1f; A.tw2f=tw2f; A.tb2f=tb2f;
  A.pw1f=pw1f; A.pb1f=pb1f; A.pw2f=pw2f; A.pb2f=pb2f;
  A.W2f=W2f; A.opwf=opwf; A.opbf=opbf; A.lngf=lngf; A.lnbf=lnbf;
  A.tw2t=tw2t; A.pw2t=pw2t; A.Wcomb=Wcomb; A.OM=OM; A.ow4=ow4;
  A.Wh1=Wh1; A.e1v=e1v; A.wadj=wadj; A.Hc=Hc;
  A.Am=Am; A.Bm=Bm; A.uvec=uvec; A.beta=beta;
  A.s2=s2; A.maxp=maxp; A.zp=zpart; A.MZ=MZ; A.gsum=gsum;
  A.htp0=htp0; A.htp1=htp1; A.hpp0=hpp0; A.hpp1=hpp1; A.hpp2=hpp2;
  A.hidden_t=hidden_t; A.hidden_p=hidden_p;
  A.tfm=tfm; A.cfm=cfm; A.H4v=H4v; A.Xp=Xp; A.out3=out3;

  {
    const void* srcs[23] = {V, prev, W1, sa1, ce_w1, ce_b1, ce_w2, ce_b2, ca0, ca1,
                            te_w1, te_b1, te_w2, te_b2, pe_w1, pe_b1, pe_w2, pe_b2,
                            W2, op_w, op_b, ln_g, ln_b};
    float* dsts[23] = {Vf, prevf, W1f, sa1f, cw1f, cb1f, cw2f, cb2f, ca0f, ca1f,
                       tw1f, tb1f, tw2f, tb2f, pw1f, pb1f, pw2f, pb2f,
                       W2f, opwf, opbf, lngf, lnbf};
    int ns[23] = {131072, 131072, 65536, 256, 131072, 256, 16384, 64, 64, 64,
                  131072, 256, 16384, 64, 196608, 256, 16384, 64,
                  98560, 65536, 256, 256, 256};
    for (int s = 0; s < 23; ++s){ A.ca.src[s] = srcs[s]; A.ca.dst[s] = dsts[s]; A.ca.n[s] = ns[s]; }
  }
  A.gs[0] = {Vf,       W1f,        Wh1,  256, 256, 256, 256};
  A.gs[1] = {Vf,       cw1f,       Am,   256, 512, 256, 256};
  A.gs[2] = {Vf,       cw1f + 256, Bm,   256, 512, 256, 256};
  A.gs[3] = {Vf,       tw1f,       htp0, 256, 512, 256, 256};
  A.gs[4] = {prevf,    tw1f + 256, htp1, 256, 512, 256, 256};
  A.gs[5] = {Xp,       pw1f,       hpp0, 768, 768, 256, 256};
  A.gs[6] = {Xp + 256, pw1f + 256, hpp1, 768, 768, 256, 256};
  A.gs[7] = {Xp + 512, pw1f + 512, hpp2, 768, 768, 256, 256};

  // ---- cooperative single-launch path ----
  bool done = false;
  int perCU = 0;
  if (hipOccupancyMaxActiveBlocksPerMultiprocessor(&perCU,
        reinterpret_cast<const void*>(&k_mega), 256, 0) != hipSuccess)
    perCU = 0;
  if (perCU > 0){
    long long grid = (long long)perCU * 256;   // 256 CUs on MI355X
    if (grid > 1216) grid = 1216;
    if (grid >= 64){
      void* prm[] = { (void*)&A };
      done = (hipLaunchCooperativeKernel(reinterpret_cast<const void*>(&k_mega),
                dim3((unsigned)grid), dim3(256), prm, 0, stream) == hipSuccess);
    }
  }

  // ---- fallback: 7-launch chain (same bodies) ----
  if (!done){
    k_stage_one<0><<<771, 256, 0, stream>>>(A);
    k_stage_one<1><<<353, 256, 0, stream>>>(A);
    k_stage_one<2><<<640, 256, 0, stream>>>(A);
    k_stage_one<3><<<1216, 256, 0, stream>>>(A);
    k_stage_one<4><<<73, 256, 0, stream>>>(A);
    k_stage_one<5><<<1152, 256, 0, stream>>>(A);
    k_stage_one<6><<<128, 256, 0, stream>>>(A);
  }
}

// Round 10
// 262.328 us; speedup vs baseline: 1.0443x; 1.0443x over previous
//
#include <hip/hip_runtime.h>

typedef unsigned short u16;

constexpr int kN   = 512;
constexpr int kIN  = 256;
constexpr int kHID = 256;
constexpr int kHD  = 64;
constexpr int kOUT = 256;

// ---------- bf16 helpers ----------
__device__ __forceinline__ float us2f(u16 u){
  union { unsigned int i; float f; } c; c.i = ((unsigned int)u) << 16; return c.f;
}
__device__ __forceinline__ u16 f2us(float f){
  union { float f; unsigned int i; } c; c.f = f;
  unsigned int r = c.i + 0x7fff + ((c.i >> 16) & 1);
  return (u16)(r >> 16);
}
__device__ __forceinline__ float ldraw(const void* p, size_t i, bool f32){
  return f32 ? ((const float*)p)[i] : us2f(((const u16*)p)[i]);
}

// ---------- per-block dtype probe (reads first 16KB of V) ----------
__device__ bool probe_is_f32(const unsigned int* __restrict__ V){
  __shared__ int cnt;
  if (threadIdx.x == 0) cnt = 0;
  __syncthreads();
  int c = 0;
  for (int k = threadIdx.x; k < 4096; k += 256){
    float x = us2f((u16)(V[k] & 0xffffu));
    if (!(fabsf(x) <= 32.0f)) c++;
  }
  atomicAdd(&cnt, c);
  __syncthreads();
  return cnt > 64;
}

// ---------- block reduction (256 threads) ----------
__device__ __forceinline__ float blk_red(float v, float* tmp, bool isMax){
  int lane = threadIdx.x & 63, wv = threadIdx.x >> 6;
  #pragma unroll
  for (int o = 32; o > 0; o >>= 1){
    float t = __shfl_down(v, o, 64);
    v = isMax ? fmaxf(v, t) : (v + t);
  }
  __syncthreads();
  if (lane == 0) tmp[wv] = v;
  __syncthreads();
  float r = tmp[0];
  for (int i = 1; i < 4; ++i) r = isMax ? fmaxf(r, tmp[i]) : (r + tmp[i]);
  return r;
}

constexpr int kNConv = 22;
struct ConvArgs { const void* src[kNConv]; float* dst[kNConv]; int n[kNConv]; };
struct GSeg2 { const float* X; const float* W; float* C; int ldx, ldw, ldc, K;
               const float* bias; int act; };
struct GS32 { const float* X; const float* W; float* C; int ldx, ldw, ldc, K; int bkn; };

struct Args {
  const unsigned int* Vraw;
  const int* adj;
  const void* rprev;
  int* flag; void* out;
  const void *rca0,*rca1,*rcw2,*rcb2,*rtw2,*rpw2;
  float *Vf,*W1f,*sa1f,*cw1f,*cb1f,*cw2f,*cb2f,*ca0f,*ca1f;
  float *tw1f,*tb1f,*tw2f,*tb2f,*pw1f,*pb1f,*pw2f,*pb2f;
  float *W2f,*opwf,*opbf,*lngf,*lnbf;
  float *tw2t,*pw2t,*Wcomb,*OM,*ow4;
  float *Wh1,*e1v,*wadj,*Hc,*Am,*Bm,*uvec,*beta;
  float *s2,*maxp,*zp,*MZ,*gsum;
  float *hidden_t,*hidden_p,*tfm,*cfm,*H4v,*Xp,*Xt,*out3;
  ConvArgs ca;
  GSeg2 gs[5];
};

// ================== GEMM-32 body: 32x32 tile, BK=32, 2x2 micro, dbuf ==================
__device__ __forceinline__ void gemm32_body(const GS32 sg, int tm, int tn, int tid,
                                            float* Xs, float* Ws)
{
  const int i0 = tm << 5, n0 = tn << 5;
  const int xrow = tid >> 3;
  const int xk = (tid & 7) << 2;
  const int rg = (tid >> 4) << 1;
  const int cg = (tid & 15) << 1;
  const float* Xb = sg.X + (size_t)i0 * sg.ldx;
  const float* Wb = sg.bkn ? (sg.W + n0) : (sg.W + (size_t)n0 * sg.ldw);
  float4 xr, wr;
  auto loadT = [&](int kt){
    xr = *(const float4*)(Xb + (size_t)xrow * sg.ldx + kt + xk);
    if (sg.bkn) wr = *(const float4*)(Wb + (size_t)(kt + xrow) * sg.ldw + xk);
    else        wr = *(const float4*)(Wb + (size_t)xrow * sg.ldw + kt + xk);
  };
  auto writeT = [&](int bu){
    float* xs = Xs + bu*1152;
    xs[(xk+0)*36 + xrow] = xr.x; xs[(xk+1)*36 + xrow] = xr.y;
    xs[(xk+2)*36 + xrow] = xr.z; xs[(xk+3)*36 + xrow] = xr.w;
    float* wsp = Ws + bu*1152;
    if (sg.bkn){
      wsp[xrow*36 + xk+0] = wr.x; wsp[xrow*36 + xk+1] = wr.y;
      wsp[xrow*36 + xk+2] = wr.z; wsp[xrow*36 + xk+3] = wr.w;
    } else {
      wsp[(xk+0)*36 + xrow] = wr.x; wsp[(xk+1)*36 + xrow] = wr.y;
      wsp[(xk+2)*36 + xrow] = wr.z; wsp[(xk+3)*36 + xrow] = wr.w;
    }
  };
  loadT(0); writeT(0); __syncthreads();
  float a00=0,a01=0,a10=0,a11=0;
  const int nkt = sg.K >> 5;
  for (int t = 0; t < nkt; ++t){
    if (t+1 < nkt) loadT((t+1) << 5);
    const float* xs = Xs + (t&1)*1152;
    const float* wsp = Ws + (t&1)*1152;
    #pragma unroll
    for (int kk = 0; kk < 32; ++kk){
      float2 av = *(const float2*)&xs[kk*36 + rg];
      float2 bv = *(const float2*)&wsp[kk*36 + cg];
      a00 += av.x*bv.x; a01 += av.x*bv.y;
      a10 += av.y*bv.x; a11 += av.y*bv.y;
    }
    if (t+1 < nkt) writeT((t+1)&1);
    __syncthreads();
  }
  float* cp = sg.C + (size_t)(i0+rg)*sg.ldc + n0 + cg;
  *(float2*)cp = make_float2(a00, a01);
  *(float2*)(cp + sg.ldc) = make_float2(a10, a11);
}

// ================== GEMM A body: 64x64 tile, BK=32, 4x4 micro, dbuf, bias/relu ==================
__device__ void body_gemmA(const Args& A, int it, int tid, char* SM)
{
  float (*Xs)[32][68] = (float (*)[32][68])SM;
  float (*Ws)[32][68] = (float (*)[32][68])(SM + 17408);
  int seg = it >> 5, x = it & 31;
  const GSeg2 sg = A.gs[seg];
  const int tm = x & 7, tn = x >> 3;
  const int i0 = tm << 6, n0 = tn << 6;

  const int xrow = tid >> 3;
  const int xk   = (tid & 7) << 2;
  const int rg = (tid >> 4) << 2;
  const int cg = (tid & 15) << 2;

  const float* Xb = sg.X + (size_t)i0 * sg.ldx;
  const float* Wb = sg.W + (size_t)n0 * sg.ldw;

  float4 xr0, xr1, wr0, wr1;
  auto loadT = [&](int kt){
    xr0 = *(const float4*)(Xb + (size_t)xrow * sg.ldx + kt + xk);
    xr1 = *(const float4*)(Xb + (size_t)(xrow+32) * sg.ldx + kt + xk);
    wr0 = *(const float4*)(Wb + (size_t)xrow * sg.ldw + kt + xk);
    wr1 = *(const float4*)(Wb + (size_t)(xrow+32) * sg.ldw + kt + xk);
  };
  auto writeT = [&](int bu){
    Xs[bu][xk+0][xrow] = xr0.x;  Xs[bu][xk+1][xrow] = xr0.y;
    Xs[bu][xk+2][xrow] = xr0.z;  Xs[bu][xk+3][xrow] = xr0.w;
    Xs[bu][xk+0][xrow+32] = xr1.x;  Xs[bu][xk+1][xrow+32] = xr1.y;
    Xs[bu][xk+2][xrow+32] = xr1.z;  Xs[bu][xk+3][xrow+32] = xr1.w;
    Ws[bu][xk+0][xrow]    = wr0.x; Ws[bu][xk+1][xrow]    = wr0.y;
    Ws[bu][xk+2][xrow]    = wr0.z; Ws[bu][xk+3][xrow]    = wr0.w;
    Ws[bu][xk+0][xrow+32] = wr1.x; Ws[bu][xk+1][xrow+32] = wr1.y;
    Ws[bu][xk+2][xrow+32] = wr1.z; Ws[bu][xk+3][xrow+32] = wr1.w;
  };

  loadT(0); writeT(0); __syncthreads();

  float acc[4][4] = {};
  const int nkt = sg.K >> 5;
  for (int t = 0; t < nkt; ++t){
    if (t + 1 < nkt) loadT((t + 1) << 5);
    const int bu = t & 1;
    #pragma unroll
    for (int kk = 0; kk < 32; ++kk){
      const float4 av = *(const float4*)&Xs[bu][kk][rg];
      const float4 bv = *(const float4*)&Ws[bu][kk][cg];
      acc[0][0]+=av.x*bv.x; acc[0][1]+=av.x*bv.y; acc[0][2]+=av.x*bv.z; acc[0][3]+=av.x*bv.w;
      acc[1][0]+=av.y*bv.x; acc[1][1]+=av.y*bv.y; acc[1][2]+=av.y*bv.z; acc[1][3]+=av.y*bv.w;
      acc[2][0]+=av.z*bv.x; acc[2][1]+=av.z*bv.y; acc[2][2]+=av.z*bv.z; acc[2][3]+=av.z*bv.w;
      acc[3][0]+=av.w*bv.x; acc[3][1]+=av.w*bv.y; acc[3][2]+=av.w*bv.z; acc[3][3]+=av.w*bv.w;
    }
    if (t + 1 < nkt) writeT((t + 1) & 1);
    __syncthreads();
  }

  float bb[4] = {0.f, 0.f, 0.f, 0.f};
  if (sg.bias){
    bb[0] = sg.bias[n0+cg+0]; bb[1] = sg.bias[n0+cg+1];
    bb[2] = sg.bias[n0+cg+2]; bb[3] = sg.bias[n0+cg+3];
  }
  #pragma unroll
  for (int ri = 0; ri < 4; ++ri){
    float4 v = make_float4(acc[ri][0]+bb[0], acc[ri][1]+bb[1],
                           acc[ri][2]+bb[2], acc[ri][3]+bb[3]);
    if (sg.act){
      v.x = fmaxf(v.x, 0.f); v.y = fmaxf(v.y, 0.f);
      v.z = fmaxf(v.z, 0.f); v.w = fmaxf(v.w, 0.f);
    }
    *(float4*)(sg.C + (size_t)(i0 + rg + ri) * sg.ldc + (n0 + cg)) = v;
  }

  // seg 0 = Wh1: fused e1 partial (e1[j] = Wh1[j,:].sa1)
  if (seg == 0){
    int cb = n0 + cg;
    float s0 = A.sa1f[cb], s1 = A.sa1f[cb+1], s2v = A.sa1f[cb+2], s3 = A.sa1f[cb+3];
    #pragma unroll
    for (int ri = 0; ri < 4; ++ri){
      float v = acc[ri][0]*s0 + acc[ri][1]*s1 + acc[ri][2]*s2v + acc[ri][3]*s3;
      v += __shfl_xor(v, 1, 16);
      v += __shfl_xor(v, 2, 16);
      v += __shfl_xor(v, 4, 16);
      v += __shfl_xor(v, 8, 16);
      if ((tid & 15) == 0) atomicAdd(&A.e1v[i0 + rg + ri], v);
    }
  }
}

// ---------- S0: [0,256) convert | [256,768) packsel(Xp+Xt) | 768 ub+zeroH4v | 769,770 transposes ----------
__global__ __launch_bounds__(256) void k_s0(Args A)
{
  __shared__ __align__(16) char SM[16896];
  int it = blockIdx.x, tid = threadIdx.x;
  bool f32 = probe_is_f32(A.Vraw);
  if (it < 256){
    if (it == 0){
      if (tid == 0) *A.flag = f32 ? 1 : 0;
      A.e1v[tid] = 0.f; A.e1v[tid + 256] = 0.f;
    }
    int t = it*256 + tid;
    for (int s = 0; s < kNConv; ++s){
      int n4 = A.ca.n[s] >> 2;
      float4* d = (float4*)A.ca.dst[s];
      if (f32){
        const float4* sf = (const float4*)A.ca.src[s];
        for (int i = t; i < n4; i += 65536) d[i] = sf[i];
      } else {
        const ushort4* sb = (const ushort4*)A.ca.src[s];
        for (int i = t; i < n4; i += 65536){
          ushort4 u = sb[i];
          d[i] = make_float4(us2f(u.x), us2f(u.y), us2f(u.z), us2f(u.w));
        }
      }
    }
  } else if (it < 768){
    unsigned long long* msk = (unsigned long long*)SM;
    int* sj = (int*)(SM + 64);
    int i = it - 256;
    int w = tid >> 6, lane = tid & 63;
    unsigned long long m0 = __ballot(A.adj[(size_t)i*kN + tid] != 0);
    unsigned long long m1 = __ballot(A.adj[(size_t)i*kN + 256 + tid] != 0);
    if (lane == 0){ msk[w] = m0; msk[4 + w] = m1; }
    __syncthreads();
    if (tid == 0){
      int j0 = -1, j1 = -1;
      for (int c = 0; c < 8 && j1 < 0; ++c){
        unsigned long long m = msk[c];
        while (m && j1 < 0){
          int bb = __builtin_ctzll(m);
          int j = c*64 + bb;
          if (j0 < 0) j0 = j; else j1 = j;
          m &= m - 1;
        }
      }
      if (j1 < 0) j0 = -1;
      sj[0] = j0; sj[1] = j1;
    }
    __syncthreads();
    int j0 = sj[0], j1 = sj[1];
    float vi = ldraw(A.Vraw, (size_t)i*kIN + tid, f32);
    A.Xp[(size_t)i*768 + tid]       = vi;
    A.Xp[(size_t)i*768 + 256 + tid] = (j0 >= 0) ? ldraw(A.Vraw, (size_t)j0*kIN + tid, f32) : 0.f;
    A.Xp[(size_t)i*768 + 512 + tid] = (j1 >= 0) ? ldraw(A.Vraw, (size_t)j1*kIN + tid, f32) : 0.f;
    A.Xt[(size_t)i*512 + tid]       = vi;
    A.Xt[(size_t)i*512 + 256 + tid] = ldraw(A.rprev, (size_t)i*kHID + tid, f32);
  } else if (it == 768){
    float* st = (float*)SM;
    if (tid < 64){ st[tid] = ldraw(A.rca0, tid, f32) + ldraw(A.rca1, tid, f32); A.H4v[tid] = 0.f; }
    __syncthreads();
    float a = 0.f;
    for (int d = 0; d < kHD; ++d) a += ldraw(A.rcw2, (size_t)d*kHID + tid, f32) * st[d];
    A.uvec[tid] = a;
    if (tid == 0){
      float b = 0.f;
      for (int d = 0; d < kHD; ++d) b += ldraw(A.rcb2, d, f32) * st[d];
      *A.beta = b;
    }
  } else {
    const void* src = (it == 769) ? A.rtw2 : A.rpw2;
    float* dst = (it == 769) ? A.tw2t : A.pw2t;
    float* st = (float*)SM;   // 64*65 floats
    for (int ch = 0; ch < 4; ++ch){
      __syncthreads();
      #pragma unroll
      for (int e = 0; e < 16; ++e){
        int lin = e*256 + tid, r = lin >> 6, c = lin & 63;
        st[r*65 + c] = ldraw(src, (size_t)r*256 + ch*64 + c, f32);
      }
      __syncthreads();
      #pragma unroll
      for (int e = 0; e < 16; ++e){
        int lin = e*256 + tid, kc = lin >> 6, dd = lin & 63;
        dst[(size_t)(ch*64 + kc)*64 + dd] = st[dd*65 + kc];
      }
    }
  }
}

// ---------- S1: [0,160) gemmA | [160,240) Wcomb | [240,256) OM | 256 ow4 ----------
__global__ __launch_bounds__(256) void k_s1(Args A)
{
  __shared__ __align__(16) char SM[34816];
  int it = blockIdx.x, tid = threadIdx.x;
  if (it < 160){
    body_gemmA(A, it, tid, SM);
  } else if (it < 240){
    int q = it - 160, tm = q & 7, tn = q >> 3;
    const float* Wsrc = A.W2f + ((tn < 8) ? 0 : 64);
    GS32 sg{A.opwf, Wsrc, A.Wcomb, 256, 385, 320, 256, 1};
    gemm32_body(sg, tm, tn, tid, (float*)SM, (float*)(SM + 9216));
  } else if (it < 256){
    int q = it - 240;
    GS32 sg{A.opwf, A.W2f + 256, A.OM, 256, 385, 64, 256, 1};
    gemm32_body(sg, q & 7, q >> 3, tid, (float*)SM, (float*)(SM + 9216));
  } else {
    float* st = (float*)SM;
    st[tid] = A.W2f[(size_t)tid*385 + 384];
    __syncthreads();
    float a = 0.f;
    const float* orow = A.opwf + (size_t)tid*256;
    for (int m = 0; m < 256; m += 4){
      float4 o4 = *(const float4*)(orow + m);
      a += o4.x*st[m] + o4.y*st[m+1] + o4.z*st[m+2] + o4.w*st[m+3];
    }
    A.ow4[tid] = a;
  }
}

// ---------- S2: [0,512) h1stats+wadj | [512,1536) s2 scores | [1536,1600) gemmB ----------
__global__ __launch_bounds__(256) void k_s2(Args A)
{
  __shared__ __align__(16) float SM2[4*256 + 256];
  int it = blockIdx.x, tid = threadIdx.x;
  if (it < 512){
    int i = it;
    int m0 = A.adj[(size_t)i*kN + tid];
    int m1 = A.adj[(size_t)i*kN + tid + 256];
    float ea = A.e1v[tid], eb = A.e1v[tid+256];
    float v0 = m0 ? ea : -1e30f;
    float v1 = m1 ? eb : -1e30f;
    float m = blk_red(fmaxf(v0, v1), SM2, true);
    float z = blk_red((m0 ? expf(ea-m) : 0.f) + (m1 ? expf(eb-m) : 0.f), SM2, false);
    float iz = 1.0f / z;
    A.wadj[(size_t)i*kN + tid]       = m0 ? expf(ea - m) * iz : 0.f;
    A.wadj[(size_t)i*kN + tid + 256] = m1 ? expf(eb - m) * iz : 0.f;
  } else if (it < 1536){
    float* aib = SM2;                 // [4][256]
    float* uu  = SM2 + 1024;          // [256]
    int q = it - 512;
    int i0 = (q & 127) * 4, j0 = (q >> 7) * 64;
    int wv = tid >> 6, lane = tid & 63;
    uu[tid] = A.uvec[tid];
    float b1v = A.cb1f[tid];
    #pragma unroll
    for (int r = 0; r < 4; ++r) aib[r*256 + tid] = A.Am[(size_t)(i0+r)*kHID + tid] + b1v;
    __syncthreads();
    int i = i0 + wv, j = j0 + lane;
    const float4* bp = (const float4*)(A.Bm + (size_t)j*kHID);
    float acc = *A.beta;
    #pragma unroll 8
    for (int k4 = 0; k4 < kHID/4; ++k4){
      float4 bv = bp[k4];
      float4 a4 = *(const float4*)&aib[wv*256 + k4*4];
      float4 u4 = *(const float4*)&uu[k4*4];
      acc += fmaxf(a4.x+bv.x,0.f)*u4.x + fmaxf(a4.y+bv.y,0.f)*u4.y
           + fmaxf(a4.z+bv.z,0.f)*u4.z + fmaxf(a4.w+bv.w,0.f)*u4.w;
    }
    if (j == i) acc = -1e30f;
    A.s2[(size_t)i*kN + j] = acc;
    float m = acc;
    #pragma unroll
    for (int o = 32; o > 0; o >>= 1) m = fmaxf(m, __shfl_down(m, o, 64));
    m = __shfl(m, 0, 64);
    float e = expf(acc - m);
    #pragma unroll
    for (int o = 32; o > 0; o >>= 1) e += __shfl_down(e, o, 64);
    if (lane == 0){
      int pb = q*4 + wv;
      A.maxp[pb] = m; A.zp[pb] = e;
    }
  } else {
    int q = it - 1536;
    int m = q >> 5, grp = q & 31;
    const float* X  = m ? A.hidden_p : A.hidden_t;
    const float* Wt = m ? A.pw2t : A.tw2t;
    const float* bi = m ? A.pb2f : A.tb2f;
    float* C = m ? A.cfm : A.tfm;
    int i0 = grp*16 + (tid >> 6)*4;
    int d = tid & 63;
    const float* x0 = X + (size_t)i0*256;
    const float* x1 = x0 + 256;
    const float* x2 = x0 + 512;
    const float* x3 = x0 + 768;
    float a0=0.f, a1=0.f, a2=0.f, a3=0.f;
    for (int k = 0; k < 256; k += 4){
      float w0 = Wt[(size_t)(k+0)*64 + d];
      float w1 = Wt[(size_t)(k+1)*64 + d];
      float w2 = Wt[(size_t)(k+2)*64 + d];
      float w3 = Wt[(size_t)(k+3)*64 + d];
      float4 f0 = *(const float4*)(x0 + k);
      float4 f1 = *(const float4*)(x1 + k);
      float4 f2 = *(const float4*)(x2 + k);
      float4 f3 = *(const float4*)(x3 + k);
      a0 += f0.x*w0 + f0.y*w1 + f0.z*w2 + f0.w*w3;
      a1 += f1.x*w0 + f1.y*w1 + f1.z*w2 + f1.w*w3;
      a2 += f2.x*w0 + f2.y*w1 + f2.z*w2 + f2.w*w3;
      a3 += f3.x*w0 + f3.y*w1 + f3.z*w2 + f3.w*w3;
    }
    float bd = bi[d];
    C[(size_t)(i0+0)*64 + d] = a0 + bd;
    C[(size_t)(i0+1)*64 + d] = a1 + bd;
    C[(size_t)(i0+2)*64 + d] = a2 + bd;
    C[(size_t)(i0+3)*64 + d] = a3 + bd;
  }
}

// ---------- S3: [0,128) H1gemm->Hc | [128,192) h3->Hc | [192,200) h4 | 200 mz+zero gsum ----------
__global__ __launch_bounds__(256) void k_s3(Args A)
{
  __shared__ __align__(16) char SM[18432];
  int it = blockIdx.x, tid = threadIdx.x;
  if (it < 128){
    GS32 sg{A.wadj, A.Wh1, A.Hc, 512, 256, 320, 512, 1};
    gemm32_body(sg, it & 15, it >> 4, tid, (float*)SM, (float*)(SM + 9216));
  } else if (it < 192){
    int d = it - 128;
    int lane = tid & 63, wv = tid >> 6;
    float v0 = A.tfm[(size_t)(2*tid)*kHD + d];
    float v1 = A.tfm[(size_t)(2*tid+1)*kHD + d];
    float s = v0 + v1;
    float x = s;
    #pragma unroll
    for (int off = 1; off < 64; off <<= 1){
      float y = __shfl_up(x, off, 64);
      if (lane >= off) x += y;
    }
    float* wsum = (float*)SM;
    if (lane == 63) wsum[wv] = x;
    __syncthreads();
    float base = 0.f;
    for (int k = 0; k < wv; ++k) base += wsum[k];
    float excl = base + x - s;
    A.Hc[(size_t)(2*tid)*320 + 256 + d]   = (excl + v0) / (float)(2*tid + 1);
    A.Hc[(size_t)(2*tid+1)*320 + 256 + d] = (excl + s)  / (float)(2*tid + 2);
  } else if (it < 200){
    float* sm = (float*)SM;
    int d = tid & 63, sub = tid >> 6;
    int r0 = (it-192)*64 + sub*16;
    float s = 0.f;
    #pragma unroll
    for (int e = 0; e < 16; ++e) s += A.cfm[(size_t)(r0+e)*kHD + d];
    sm[sub*64 + d] = s;
    __syncthreads();
    if (tid < 64)
      atomicAdd(&A.H4v[tid], sm[tid] + sm[64+tid] + sm[128+tid] + sm[192+tid]);
  } else {
    float* red = (float*)SM;
    float m = -1e30f;
    #pragma unroll
    for (int r = 0; r < 16; ++r) m = fmaxf(m, A.maxp[tid + 256*r]);
    m = blk_red(m, red, true);
    float z = 0.f;
    #pragma unroll
    for (int r = 0; r < 16; ++r) z += A.zp[tid + 256*r] * expf(A.maxp[tid + 256*r] - m);
    z = blk_red(z, red, false);
    if (tid == 0){ A.MZ[0] = m; A.MZ[1] = z; }
    A.gsum[tid] = 0.f;
  }
}

// ---------- S4: [0,1024) gpart | [1024,1152) out3 (Hc @ Wcomb^T) ----------
__global__ __launch_bounds__(256) void k_s4(Args A)
{
  __shared__ __align__(16) char SM[18432];
  int it = blockIdx.x, tid = threadIdx.x;
  if (it < 1024){
    float* wt = (float*)SM;             // [16][16]
    int i0 = (it & 31) * 16, j0 = (it >> 5) * 16;
    float M = A.MZ[0], invZ = 1.0f / A.MZ[1];
    {
      int r = tid >> 4, c = tid & 15;
      wt[r*16 + c] = expf(A.s2[(size_t)(i0+r)*kN + (j0+c)] - M) * invZ;
    }
    float b1v = A.cb1f[tid];
    float aib[16];
    #pragma unroll
    for (int r = 0; r < 16; ++r) aib[r] = A.Am[(size_t)(i0+r)*kHID + tid] + b1v;
    __syncthreads();
    float acc = 0.f;
    for (int j = 0; j < 16; ++j){
      float bj = A.Bm[(size_t)(j0+j)*kHID + tid];
      #pragma unroll
      for (int r = 0; r < 16; ++r)
        acc += wt[r*16 + j] * fmaxf(aib[r] + bj, 0.f);
    }
    atomicAdd(&A.gsum[tid], acc);
  } else {
    int q = it - 1024;
    GS32 sg{A.Hc, A.Wcomb, A.out3, 320, 320, 256, 320, 0};
    gemm32_body(sg, q & 15, q >> 4, tid, (float*)SM, (float*)(SM + 9216));
  }
}

// ---------- S5: final (H2vec/cc2 recompute + rank-1 adds + LN + ELU), grid 128 ----------
__global__ __launch_bounds__(256) void k_s5(Args A)
{
  __shared__ float gs[kHID];
  __shared__ float part[kHD][4];
  __shared__ float h2s[kHD];
  __shared__ float cc2s[kOUT];
  int b = blockIdx.x, tid = threadIdx.x;
  bool f32 = (*A.flag != 0);
  gs[tid] = A.gsum[tid];
  __syncthreads();
  {
    int dd = tid >> 2, q = tid & 3;
    float a = 0.f;
    for (int kk = 0; kk < 64; ++kk){
      int k = q*64 + kk;
      a += gs[k] * A.cw2f[(size_t)dd*kHID + k];
    }
    part[dd][q] = a;
  }
  __syncthreads();
  if (tid < kHD)
    h2s[tid] = A.cb2f[tid] + part[tid][0] + part[tid][1] + part[tid][2] + part[tid][3];
  __syncthreads();
  {
    float a = 0.f;
    const float* om = A.OM + (size_t)tid*64;
    for (int d = 0; d < kHD; d += 4){
      float4 o4 = *(const float4*)(om + d);
      a += o4.x*h2s[d] + o4.y*h2s[d+1] + o4.z*h2s[d+2] + o4.w*h2s[d+3];
    }
    cc2s[tid] = a;
  }
  __syncthreads();
  int row = b*4 + (tid >> 6), lane = tid & 63;
  float h4r = (row < kHD) ? A.H4v[row] : 0.f;
  float4 v  = *(const float4*)(A.out3 + (size_t)row*kOUT + lane*4);
  float4 c2 = *(const float4*)(&cc2s[lane*4]);
  float4 o4 = *(const float4*)(A.ow4 + lane*4);
  float4 pb = *(const float4*)(A.opbf + lane*4);
  v.x += c2.x + h4r*o4.x + pb.x;
  v.y += c2.y + h4r*o4.y + pb.y;
  v.z += c2.z + h4r*o4.z + pb.z;
  v.w += c2.w + h4r*o4.w + pb.w;
  float s = v.x + v.y + v.z + v.w;
  #pragma unroll
  for (int o = 32; o > 0; o >>= 1) s += __shfl_xor(s, o, 64);
  float mu = s * (1.0f/kOUT);
  float dx = v.x-mu, dy = v.y-mu, dz = v.z-mu, dw = v.w-mu;
  float ss = dx*dx + dy*dy + dz*dz + dw*dw;
  #pragma unroll
  for (int o = 32; o > 0; o >>= 1) ss += __shfl_xor(ss, o, 64);
  float rs = rsqrtf(ss * (1.0f/kOUT) + 1e-5f);
  float4 g  = *(const float4*)(A.lngf + lane*4);
  float4 be = *(const float4*)(A.lnbf + lane*4);
  float y0 = dx*rs*g.x + be.x, y1 = dy*rs*g.y + be.y;
  float y2 = dz*rs*g.z + be.z, y3 = dw*rs*g.w + be.w;
  y0 = (y0 > 0.f) ? y0 : expm1f(y0);
  y1 = (y1 > 0.f) ? y1 : expm1f(y1);
  y2 = (y2 > 0.f) ? y2 : expm1f(y2);
  y3 = (y3 > 0.f) ? y3 : expm1f(y3);
  if (f32){
    *(float4*)((float*)A.out + (size_t)row*kOUT + lane*4) = make_float4(y0,y1,y2,y3);
  } else {
    ushort4 u; u.x = f2us(y0); u.y = f2us(y1); u.z = f2us(y2); u.w = f2us(y3);
    ((ushort4*)A.out)[(size_t)row*64 + lane] = u;
  }
}

extern "C" void kernel_launch(void* const* d_in, const int* in_sizes, int n_in,
                              void* d_out, int out_size, void* d_ws, size_t ws_size,
                              hipStream_t stream)
{
  const void* V     = d_in[0];
  const int*  adj   = (const int*)d_in[1];
  const void* prev  = d_in[2];
  const void* W1    = d_in[3];
  // d_in[4] = sa0 : dead (row-shift invariant softmax)
  const void* sa1   = d_in[5];
  const void* ce_w1 = d_in[6];
  const void* ce_b1 = d_in[7];
  const void* ce_w2 = d_in[8];
  const void* ce_b2 = d_in[9];
  const void* ca0   = d_in[10];
  const void* ca1   = d_in[11];
  const void* te_w1 = d_in[12];
  const void* te_b1 = d_in[13];
  const void* te_w2 = d_in[14];
  const void* te_b2 = d_in[15];
  // d_in[16,17] = ta0,ta1 : dead
  const void* pe_w1 = d_in[18];
  const void* pe_b1 = d_in[19];
  const void* pe_w2 = d_in[20];
  const void* pe_b2 = d_in[21];
  // d_in[22,23] = pa0,pa1 : dead
  const void* W2    = d_in[24];
  const void* op_w  = d_in[25];
  const void* op_b  = d_in[26];
  const void* ln_g  = d_in[27];
  const void* ln_b  = d_in[28];

  // ---- workspace layout (floats) ----
  float* ws  = (float*)d_ws;
  int*  flag = (int*)ws;               // 16 floats reserved
  float* p   = ws + 16;
  float* Vf   = p; p += 131072;
  float* W1f  = p; p += 65536;
  float* sa1f = p; p += 256;
  float* cw1f = p; p += 131072;
  float* cb1f = p; p += 256;
  float* cw2f = p; p += 16384;
  float* cb2f = p; p += 64;
  float* ca0f = p; p += 64;
  float* ca1f = p; p += 64;
  float* tw1f = p; p += 131072;
  float* tb1f = p; p += 256;
  float* tw2f = p; p += 16384;
  float* tb2f = p; p += 64;
  float* pw1f = p; p += 196608;
  float* pb1f = p; p += 256;
  float* pw2f = p; p += 16384;
  float* pb2f = p; p += 64;
  float* W2f  = p; p += 98560;
  float* opwf = p; p += 65536;
  float* opbf = p; p += 256;
  float* lngf = p; p += 256;
  float* lnbf = p; p += 256;
  float* tw2t = p; p += 16384;
  float* pw2t = p; p += 16384;
  float* Wcomb= p; p += 81920;
  float* OM   = p; p += 16384;
  float* ow4  = p; p += 256;
  float* Wh1      = p; p += 131072;
  float* e1v      = p; p += 512;
  float* wadj     = p; p += 262144;
  float* Hc       = p; p += 163840;
  float* Am       = p; p += 131072;
  float* Bm       = p; p += 131072;
  float* uvec     = p; p += 256;
  float* beta     = p; p += 16;
  float* s2       = p; p += 262144;
  float* maxp     = p; p += 4096;
  float* zpart    = p; p += 4096;
  float* MZ       = p; p += 16;
  float* gsum     = p; p += 256;
  float* hidden_t = p; p += 131072;
  float* hidden_p = p; p += 131072;
  float* tfm      = p; p += 32768;
  float* cfm      = p; p += 32768;
  float* H4v      = p; p += 64;
  float* Xp       = p; p += 393216;
  float* Xt       = p; p += 262144;
  float* out3     = p; p += 131072;

  // ---- args bundle ----
  Args A;
  A.Vraw = (const unsigned int*)V; A.adj = adj; A.rprev = prev;
  A.flag = flag; A.out = d_out;
  A.rca0 = ca0; A.rca1 = ca1; A.rcw2 = ce_w2; A.rcb2 = ce_b2; A.rtw2 = te_w2; A.rpw2 = pe_w2;
  A.Vf=Vf; A.W1f=W1f; A.sa1f=sa1f; A.cw1f=cw1f; A.cb1f=cb1f;
  A.cw2f=cw2f; A.cb2f=cb2f; A.ca0f=ca0f; A.ca1f=ca1f;
  A.tw1f=tw1f; A.tb1f=tb1f; A.tw2f=tw2f; A.tb2f=tb2f;
  A.pw1f=pw1f; A.pb1f=pb1f; A.pw2f=pw2f; A.pb2f=pb2f;
  A.W2f=W2f; A.opwf=opwf; A.opbf=opbf; A.lngf=lngf; A.lnbf=lnbf;
  A.tw2t=tw2t; A.pw2t=pw2t; A.Wcomb=Wcomb; A.OM=OM; A.ow4=ow4;
  A.Wh1=Wh1; A.e1v=e1v; A.wadj=wadj; A.Hc=Hc;
  A.Am=Am; A.Bm=Bm; A.uvec=uvec; A.beta=beta;
  A.s2=s2; A.maxp=maxp; A.zp=zpart; A.MZ=MZ; A.gsum=gsum;
  A.hidden_t=hidden_t; A.hidden_p=hidden_p;
  A.tfm=tfm; A.cfm=cfm; A.H4v=H4v; A.Xp=Xp; A.Xt=Xt; A.out3=out3;

  {
    const void* srcs[kNConv] = {V, W1, sa1, ce_w1, ce_b1, ce_w2, ce_b2, ca0, ca1,
                                te_w1, te_b1, te_w2, te_b2, pe_w1, pe_b1, pe_w2, pe_b2,
                                W2, op_w, op_b, ln_g, ln_b};
    float* dsts[kNConv] = {Vf, W1f, sa1f, cw1f, cb1f, cw2f, cb2f, ca0f, ca1f,
                           tw1f, tb1f, tw2f, tb2f, pw1f, pb1f, pw2f, pb2f,
                           W2f, opwf, opbf, lngf, lnbf};
    int ns[kNConv] = {131072, 65536, 256, 131072, 256, 16384, 64, 64, 64,
                      131072, 256, 16384, 64, 196608, 256, 16384, 64,
                      98560, 65536, 256, 256, 256};
    for (int s = 0; s < kNConv; ++s){ A.ca.src[s] = srcs[s]; A.ca.dst[s] = dsts[s]; A.ca.n[s] = ns[s]; }
  }
  // gemmA segments: Wh1 / Am / Bm (K=256), hidden_t (K=512, Xt, bias+relu),
  // hidden_p (K=768, Xp, bias+relu)
  A.gs[0] = {Vf, W1f,        Wh1,      256, 256, 256, 256, nullptr, 0};
  A.gs[1] = {Vf, cw1f,       Am,       256, 512, 256, 256, nullptr, 0};
  A.gs[2] = {Vf, cw1f + 256, Bm,       256, 512, 256, 256, nullptr, 0};
  A.gs[3] = {Xt, tw1f,       hidden_t, 512, 512, 256, 512, tb1f, 1};
  A.gs[4] = {Xp, pw1f,       hidden_p, 768, 768, 256, 768, pb1f, 1};

  // ---- 6-launch chain ----
  k_s0<<<771,  256, 0, stream>>>(A);
  k_s1<<<257,  256, 0, stream>>>(A);
  k_s2<<<1600, 256, 0, stream>>>(A);
  k_s3<<<201,  256, 0, stream>>>(A);
  k_s4<<<1152, 256, 0, stream>>>(A);
  k_s5<<<128,  256, 0, stream>>>(A);
}

// Round 11
// 254.631 us; speedup vs baseline: 1.0759x; 1.0302x over previous
//
#include <hip/hip_runtime.h>

typedef unsigned short u16;

constexpr int kN   = 512;
constexpr int kIN  = 256;
constexpr int kHID = 256;
constexpr int kHD  = 64;
constexpr int kOUT = 256;

// ---------- bf16 helpers ----------
__device__ __forceinline__ float us2f(u16 u){
  union { unsigned int i; float f; } c; c.i = ((unsigned int)u) << 16; return c.f;
}
__device__ __forceinline__ u16 f2us(float f){
  union { float f; unsigned int i; } c; c.f = f;
  unsigned int r = c.i + 0x7fff + ((c.i >> 16) & 1);
  return (u16)(r >> 16);
}
__device__ __forceinline__ float ldraw(const void* p, size_t i, bool f32){
  return f32 ? ((const float*)p)[i] : us2f(((const u16*)p)[i]);
}

// ---------- per-block dtype probe (reads first 16KB of V) ----------
__device__ bool probe_is_f32(const unsigned int* __restrict__ V){
  __shared__ int cnt;
  if (threadIdx.x == 0) cnt = 0;
  __syncthreads();
  int c = 0;
  for (int k = threadIdx.x; k < 4096; k += 256){
    float x = us2f((u16)(V[k] & 0xffffu));
    if (!(fabsf(x) <= 32.0f)) c++;
  }
  atomicAdd(&cnt, c);
  __syncthreads();
  return cnt > 64;
}

// ---------- block reduction (256 threads) ----------
__device__ __forceinline__ float blk_red(float v, float* tmp, bool isMax){
  int lane = threadIdx.x & 63, wv = threadIdx.x >> 6;
  #pragma unroll
  for (int o = 32; o > 0; o >>= 1){
    float t = __shfl_down(v, o, 64);
    v = isMax ? fmaxf(v, t) : (v + t);
  }
  __syncthreads();
  if (lane == 0) tmp[wv] = v;
  __syncthreads();
  float r = tmp[0];
  for (int i = 1; i < 4; ++i) r = isMax ? fmaxf(r, tmp[i]) : (r + tmp[i]);
  return r;
}

constexpr int kNConv = 23;
struct ConvArgs { const void* src[kNConv]; float* dst[kNConv]; int n[kNConv]; };
struct GSeg2 { const float* X; const float* W; float* C; int ldx, ldw, ldc, K; };
struct GS32 { const float* X; const float* W; float* C; int ldx, ldw, ldc, K; int bkn; };

struct Args {
  const unsigned int* Vraw;
  const int* adj;
  int* flag; void* out;
  const void *rca0,*rca1,*rcw2,*rcb2,*rtw2,*rpw2;
  float *Vf,*prevf,*W1f,*sa1f,*cw1f,*cb1f,*cw2f,*cb2f,*ca0f,*ca1f;
  float *tw1f,*tb1f,*tw2f,*tb2f,*pw1f,*pb1f,*pw2f,*pb2f;
  float *W2f,*opwf,*opbf,*lngf,*lnbf;
  float *tw2t,*pw2t,*Wcomb,*OM,*ow4;
  float *Wh1,*e1v,*wadj,*Hc,*Am,*Bm,*uvec,*beta;
  float *s2,*maxp,*zp,*MZ,*gsum;
  float *htp0,*htp1,*hpp0,*hpp1,*hpp2,*hidden_t,*hidden_p;
  float *tfm,*cfm,*H4v,*Xp,*out3;
  ConvArgs ca;
  GSeg2 gs[8];
};

// ================== GEMM-32 body: 32x32 tile, BK=32, 2x2 micro, dbuf ==================
__device__ __forceinline__ void gemm32_body(const GS32 sg, int tm, int tn, int tid,
                                            float* Xs, float* Ws)
{
  const int i0 = tm << 5, n0 = tn << 5;
  const int xrow = tid >> 3;
  const int xk = (tid & 7) << 2;
  const int rg = (tid >> 4) << 1;
  const int cg = (tid & 15) << 1;
  const float* Xb = sg.X + (size_t)i0 * sg.ldx;
  const float* Wb = sg.bkn ? (sg.W + n0) : (sg.W + (size_t)n0 * sg.ldw);
  float4 xr, wr;
  auto loadT = [&](int kt){
    xr = *(const float4*)(Xb + (size_t)xrow * sg.ldx + kt + xk);
    if (sg.bkn) wr = *(const float4*)(Wb + (size_t)(kt + xrow) * sg.ldw + xk);
    else        wr = *(const float4*)(Wb + (size_t)xrow * sg.ldw + kt + xk);
  };
  auto writeT = [&](int bu){
    float* xs = Xs + bu*1152;
    xs[(xk+0)*36 + xrow] = xr.x; xs[(xk+1)*36 + xrow] = xr.y;
    xs[(xk+2)*36 + xrow] = xr.z; xs[(xk+3)*36 + xrow] = xr.w;
    float* wsp = Ws + bu*1152;
    if (sg.bkn){
      wsp[xrow*36 + xk+0] = wr.x; wsp[xrow*36 + xk+1] = wr.y;
      wsp[xrow*36 + xk+2] = wr.z; wsp[xrow*36 + xk+3] = wr.w;
    } else {
      wsp[(xk+0)*36 + xrow] = wr.x; wsp[(xk+1)*36 + xrow] = wr.y;
      wsp[(xk+2)*36 + xrow] = wr.z; wsp[(xk+3)*36 + xrow] = wr.w;
    }
  };
  loadT(0); writeT(0); __syncthreads();
  float a00=0,a01=0,a10=0,a11=0;
  const int nkt = sg.K >> 5;
  for (int t = 0; t < nkt; ++t){
    if (t+1 < nkt) loadT((t+1) << 5);
    const float* xs = Xs + (t&1)*1152;
    const float* wsp = Ws + (t&1)*1152;
    #pragma unroll
    for (int kk = 0; kk < 32; ++kk){
      float2 av = *(const float2*)&xs[kk*36 + rg];
      float2 bv = *(const float2*)&wsp[kk*36 + cg];
      a00 += av.x*bv.x; a01 += av.x*bv.y;
      a10 += av.y*bv.x; a11 += av.y*bv.y;
    }
    if (t+1 < nkt) writeT((t+1)&1);
    __syncthreads();
  }
  float* cp = sg.C + (size_t)(i0+rg)*sg.ldc + n0 + cg;
  *(float2*)cp = make_float2(a00, a01);
  *(float2*)(cp + sg.ldc) = make_float2(a10, a11);
}

// ================== GEMM A body: 64x64 tile, BK=32, 4x4 micro, dbuf ==================
__device__ void body_gemmA(const Args& A, int it, int tid, char* SM)
{
  float (*Xs)[32][68] = (float (*)[32][68])SM;
  float (*Ws)[32][68] = (float (*)[32][68])(SM + 17408);
  int seg = it >> 5, x = it & 31;
  const GSeg2 sg = A.gs[seg];
  const int tm = x & 7, tn = x >> 3;
  const int i0 = tm << 6, n0 = tn << 6;

  const int xrow = tid >> 3;
  const int xk   = (tid & 7) << 2;
  const int rg = (tid >> 4) << 2;
  const int cg = (tid & 15) << 2;

  const float* Xb = sg.X + (size_t)i0 * sg.ldx;
  const float* Wb = sg.W + (size_t)n0 * sg.ldw;

  float4 xr0, xr1, wr0, wr1;
  auto loadT = [&](int kt){
    xr0 = *(const float4*)(Xb + (size_t)xrow * sg.ldx + kt + xk);
    xr1 = *(const float4*)(Xb + (size_t)(xrow+32) * sg.ldx + kt + xk);
    wr0 = *(const float4*)(Wb + (size_t)xrow * sg.ldw + kt + xk);
    wr1 = *(const float4*)(Wb + (size_t)(xrow+32) * sg.ldw + kt + xk);
  };
  auto writeT = [&](int bu){
    Xs[bu][xk+0][xrow] = xr0.x;  Xs[bu][xk+1][xrow] = xr0.y;
    Xs[bu][xk+2][xrow] = xr0.z;  Xs[bu][xk+3][xrow] = xr0.w;
    Xs[bu][xk+0][xrow+32] = xr1.x;  Xs[bu][xk+1][xrow+32] = xr1.y;
    Xs[bu][xk+2][xrow+32] = xr1.z;  Xs[bu][xk+3][xrow+32] = xr1.w;
    Ws[bu][xk+0][xrow]    = wr0.x; Ws[bu][xk+1][xrow]    = wr0.y;
    Ws[bu][xk+2][xrow]    = wr0.z; Ws[bu][xk+3][xrow]    = wr0.w;
    Ws[bu][xk+0][xrow+32] = wr1.x; Ws[bu][xk+1][xrow+32] = wr1.y;
    Ws[bu][xk+2][xrow+32] = wr1.z; Ws[bu][xk+3][xrow+32] = wr1.w;
  };

  loadT(0); writeT(0); __syncthreads();

  float acc[4][4] = {};
  const int nkt = sg.K >> 5;
  for (int t = 0; t < nkt; ++t){
    if (t + 1 < nkt) loadT((t + 1) << 5);
    const int bu = t & 1;
    #pragma unroll
    for (int kk = 0; kk < 32; ++kk){
      const float4 av = *(const float4*)&Xs[bu][kk][rg];
      const float4 bv = *(const float4*)&Ws[bu][kk][cg];
      acc[0][0]+=av.x*bv.x; acc[0][1]+=av.x*bv.y; acc[0][2]+=av.x*bv.z; acc[0][3]+=av.x*bv.w;
      acc[1][0]+=av.y*bv.x; acc[1][1]+=av.y*bv.y; acc[1][2]+=av.y*bv.z; acc[1][3]+=av.y*bv.w;
      acc[2][0]+=av.z*bv.x; acc[2][1]+=av.z*bv.y; acc[2][2]+=av.z*bv.z; acc[2][3]+=av.z*bv.w;
      acc[3][0]+=av.w*bv.x; acc[3][1]+=av.w*bv.y; acc[3][2]+=av.w*bv.z; acc[3][3]+=av.w*bv.w;
    }
    if (t + 1 < nkt) writeT((t + 1) & 1);
    __syncthreads();
  }

  #pragma unroll
  for (int ri = 0; ri < 4; ++ri)
    *(float4*)(sg.C + (size_t)(i0 + rg + ri) * sg.ldc + (n0 + cg)) =
      make_float4(acc[ri][0], acc[ri][1], acc[ri][2], acc[ri][3]);

  // seg 0 = Wh1: fused e1 partial (e1[j] = Wh1[j,:].sa1)
  if (seg == 0){
    int cb = n0 + cg;
    float s0 = A.sa1f[cb], s1 = A.sa1f[cb+1], s2v = A.sa1f[cb+2], s3 = A.sa1f[cb+3];
    #pragma unroll
    for (int ri = 0; ri < 4; ++ri){
      float v = acc[ri][0]*s0 + acc[ri][1]*s1 + acc[ri][2]*s2v + acc[ri][3]*s3;
      v += __shfl_xor(v, 1, 16);
      v += __shfl_xor(v, 2, 16);
      v += __shfl_xor(v, 4, 16);
      v += __shfl_xor(v, 8, 16);
      if ((tid & 15) == 0) atomicAdd(&A.e1v[i0 + rg + ri], v);
    }
  }
}

// ---------- S0: [0,256) convert | [256,768) packsel(Xp) | 768 ub+zeroH4v | 769,770 transposes ----------
__global__ __launch_bounds__(256) void k_s0(Args A)
{
  __shared__ __align__(16) char SM[16896];
  int it = blockIdx.x, tid = threadIdx.x;
  bool f32 = probe_is_f32(A.Vraw);
  if (it < 256){
    if (it == 0){
      if (tid == 0) *A.flag = f32 ? 1 : 0;
      A.e1v[tid] = 0.f; A.e1v[tid + 256] = 0.f;
    }
    int t = it*256 + tid;
    for (int s = 0; s < kNConv; ++s){
      int n4 = A.ca.n[s] >> 2;
      float4* d = (float4*)A.ca.dst[s];
      if (f32){
        const float4* sf = (const float4*)A.ca.src[s];
        for (int i = t; i < n4; i += 65536) d[i] = sf[i];
      } else {
        const ushort4* sb = (const ushort4*)A.ca.src[s];
        for (int i = t; i < n4; i += 65536){
          ushort4 u = sb[i];
          d[i] = make_float4(us2f(u.x), us2f(u.y), us2f(u.z), us2f(u.w));
        }
      }
    }
  } else if (it < 768){
    unsigned long long* msk = (unsigned long long*)SM;
    int* sj = (int*)(SM + 64);
    int i = it - 256;
    int w = tid >> 6, lane = tid & 63;
    unsigned long long m0 = __ballot(A.adj[(size_t)i*kN + tid] != 0);
    unsigned long long m1 = __ballot(A.adj[(size_t)i*kN + 256 + tid] != 0);
    if (lane == 0){ msk[w] = m0; msk[4 + w] = m1; }
    __syncthreads();
    if (tid == 0){
      int j0 = -1, j1 = -1;
      for (int c = 0; c < 8 && j1 < 0; ++c){
        unsigned long long m = msk[c];
        while (m && j1 < 0){
          int bb = __builtin_ctzll(m);
          int j = c*64 + bb;
          if (j0 < 0) j0 = j; else j1 = j;
          m &= m - 1;
        }
      }
      if (j1 < 0) j0 = -1;
      sj[0] = j0; sj[1] = j1;
    }
    __syncthreads();
    int j0 = sj[0], j1 = sj[1];
    A.Xp[(size_t)i*768 + tid]       = ldraw(A.Vraw, (size_t)i*kIN + tid, f32);
    A.Xp[(size_t)i*768 + 256 + tid] = (j0 >= 0) ? ldraw(A.Vraw, (size_t)j0*kIN + tid, f32) : 0.f;
    A.Xp[(size_t)i*768 + 512 + tid] = (j1 >= 0) ? ldraw(A.Vraw, (size_t)j1*kIN + tid, f32) : 0.f;
  } else if (it == 768){
    float* st = (float*)SM;
    if (tid < 64){ st[tid] = ldraw(A.rca0, tid, f32) + ldraw(A.rca1, tid, f32); A.H4v[tid] = 0.f; }
    __syncthreads();
    float a = 0.f;
    for (int d = 0; d < kHD; ++d) a += ldraw(A.rcw2, (size_t)d*kHID + tid, f32) * st[d];
    A.uvec[tid] = a;
    if (tid == 0){
      float b = 0.f;
      for (int d = 0; d < kHD; ++d) b += ldraw(A.rcb2, d, f32) * st[d];
      *A.beta = b;
    }
  } else {
    const void* src = (it == 769) ? A.rtw2 : A.rpw2;
    float* dst = (it == 769) ? A.tw2t : A.pw2t;
    float* st = (float*)SM;   // 64*65 floats
    for (int ch = 0; ch < 4; ++ch){
      __syncthreads();
      #pragma unroll
      for (int e = 0; e < 16; ++e){
        int lin = e*256 + tid, r = lin >> 6, c = lin & 63;
        st[r*65 + c] = ldraw(src, (size_t)r*256 + ch*64 + c, f32);
      }
      __syncthreads();
      #pragma unroll
      for (int e = 0; e < 16; ++e){
        int lin = e*256 + tid, kc = lin >> 6, dd = lin & 63;
        dst[(size_t)(ch*64 + kc)*64 + dd] = st[dd*65 + kc];
      }
    }
  }
}

// ---------- S1: [0,256) gemmA(+e1) | [256,336) Wcomb | [336,352) OM | 352 ow4 ----------
__global__ __launch_bounds__(256) void k_s1(Args A)
{
  __shared__ __align__(16) char SM[34816];
  int it = blockIdx.x, tid = threadIdx.x;
  if (it < 256){
    body_gemmA(A, it, tid, SM);
  } else if (it < 336){
    int q = it - 256, tm = q & 7, tn = q >> 3;
    const float* Wsrc = A.W2f + ((tn < 8) ? 0 : 64);
    GS32 sg{A.opwf, Wsrc, A.Wcomb, 256, 385, 320, 256, 1};
    gemm32_body(sg, tm, tn, tid, (float*)SM, (float*)(SM + 9216));
  } else if (it < 352){
    int q = it - 336;
    GS32 sg{A.opwf, A.W2f + 256, A.OM, 256, 385, 64, 256, 1};
    gemm32_body(sg, q & 7, q >> 3, tid, (float*)SM, (float*)(SM + 9216));
  } else {
    float* st = (float*)SM;
    st[tid] = A.W2f[(size_t)tid*385 + 384];
    __syncthreads();
    float a = 0.f;
    const float* orow = A.opwf + (size_t)tid*256;
    for (int m = 0; m < 256; m += 4){
      float4 o4 = *(const float4*)(orow + m);
      a += o4.x*st[m] + o4.y*st[m+1] + o4.z*st[m+2] + o4.w*st[m+3];
    }
    A.ow4[tid] = a;
  }
}

// ---------- S2: [0,128) redH | [128,640) h1stats+wadj ----------
__global__ __launch_bounds__(256) void k_s2(Args A)
{
  __shared__ float SM2[8];
  int it = blockIdx.x, tid = threadIdx.x;
  if (it < 128){
    int f = it*256 + tid;
    int c4 = f & 63;
    {
      float4 a = ((const float4*)A.htp0)[f], bb = ((const float4*)A.htp1)[f];
      float4 bi = ((const float4*)A.tb1f)[c4];
      ((float4*)A.hidden_t)[f] = make_float4(
        fmaxf(a.x+bb.x+bi.x,0.f), fmaxf(a.y+bb.y+bi.y,0.f),
        fmaxf(a.z+bb.z+bi.z,0.f), fmaxf(a.w+bb.w+bi.w,0.f));
    }
    {
      float4 a = ((const float4*)A.hpp0)[f], bb = ((const float4*)A.hpp1)[f];
      float4 c = ((const float4*)A.hpp2)[f];
      float4 bi = ((const float4*)A.pb1f)[c4];
      ((float4*)A.hidden_p)[f] = make_float4(
        fmaxf(a.x+bb.x+c.x+bi.x,0.f), fmaxf(a.y+bb.y+c.y+bi.y,0.f),
        fmaxf(a.z+bb.z+c.z+bi.z,0.f), fmaxf(a.w+bb.w+c.w+bi.w,0.f));
    }
  } else {
    int i = it - 128;
    int m0 = A.adj[(size_t)i*kN + tid];
    int m1 = A.adj[(size_t)i*kN + tid + 256];
    float ea = A.e1v[tid], eb = A.e1v[tid+256];
    float v0 = m0 ? ea : -1e30f;
    float v1 = m1 ? eb : -1e30f;
    float m = blk_red(fmaxf(v0, v1), SM2, true);
    float z = blk_red((m0 ? expf(ea-m) : 0.f) + (m1 ? expf(eb-m) : 0.f), SM2, false);
    float iz = 1.0f / z;
    A.wadj[(size_t)i*kN + tid]       = m0 ? expf(ea - m) * iz : 0.f;
    A.wadj[(size_t)i*kN + tid + 256] = m1 ? expf(eb - m) * iz : 0.f;
  }
}

// ---------- S3: [0,64) gemmB(reg) | [64,576) s2 scores (coalesced wave-per-j) ----------
__global__ __launch_bounds__(256) void k_s3(Args A)
{
  __shared__ __align__(16) float SM3[4*256 + 256];
  int it = blockIdx.x, tid = threadIdx.x;
  if (it < 64){
    int m = it >> 5, grp = it & 31;
    const float* X  = m ? A.hidden_p : A.hidden_t;
    const float* Wt = m ? A.pw2t : A.tw2t;
    const float* bi = m ? A.pb2f : A.tb2f;
    float* C = m ? A.cfm : A.tfm;
    int i0 = grp*16 + (tid >> 6)*4;
    int d = tid & 63;
    const float* x0 = X + (size_t)i0*256;
    const float* x1 = x0 + 256;
    const float* x2 = x0 + 512;
    const float* x3 = x0 + 768;
    float a0=0.f, a1=0.f, a2=0.f, a3=0.f;
    for (int k = 0; k < 256; k += 4){
      float w0 = Wt[(size_t)(k+0)*64 + d];
      float w1 = Wt[(size_t)(k+1)*64 + d];
      float w2 = Wt[(size_t)(k+2)*64 + d];
      float w3 = Wt[(size_t)(k+3)*64 + d];
      float4 f0 = *(const float4*)(x0 + k);
      float4 f1 = *(const float4*)(x1 + k);
      float4 f2 = *(const float4*)(x2 + k);
      float4 f3 = *(const float4*)(x3 + k);
      a0 += f0.x*w0 + f0.y*w1 + f0.z*w2 + f0.w*w3;
      a1 += f1.x*w0 + f1.y*w1 + f1.z*w2 + f1.w*w3;
      a2 += f2.x*w0 + f2.y*w1 + f2.z*w2 + f2.w*w3;
      a3 += f3.x*w0 + f3.y*w1 + f3.z*w2 + f3.w*w3;
    }
    float bd = bi[d];
    C[(size_t)(i0+0)*64 + d] = a0 + bd;
    C[(size_t)(i0+1)*64 + d] = a1 + bd;
    C[(size_t)(i0+2)*64 + d] = a2 + bd;
    C[(size_t)(i0+3)*64 + d] = a3 + bd;
  } else {
    // Block: 4 i-rows x 128 j; each wave owns 32 j. Lane = k-quad (coalesced Bm row read).
    float* aib = SM3;                 // [4][256]
    float* uu  = SM3 + 1024;          // [256]
    int q = it - 64;                  // 0..511
    int i0 = (q & 127) * 4, jt = q >> 7;
    int w = tid >> 6, lane = tid & 63;
    uu[tid] = A.uvec[tid];
    float b1v = A.cb1f[tid];
    #pragma unroll
    for (int r = 0; r < 4; ++r) aib[r*256 + tid] = A.Am[(size_t)(i0+r)*kHID + tid] + b1v;
    __syncthreads();
    float bet = *A.beta;
    float4 u4 = *(const float4*)&uu[lane*4];
    float4 a4[4];
    #pragma unroll
    for (int r = 0; r < 4; ++r) a4[r] = *(const float4*)&aib[r*256 + lane*4];
    float sv[4] = {-1e30f, -1e30f, -1e30f, -1e30f};
    int jbase = jt*128 + w*32;
    for (int jj = 0; jj < 32; ++jj){
      int j = jbase + jj;
      float4 bv = *(const float4*)(A.Bm + (size_t)j*kHID + lane*4);
      #pragma unroll
      for (int r = 0; r < 4; ++r){
        float p = fmaxf(a4[r].x+bv.x,0.f)*u4.x + fmaxf(a4[r].y+bv.y,0.f)*u4.y
                + fmaxf(a4[r].z+bv.z,0.f)*u4.z + fmaxf(a4[r].w+bv.w,0.f)*u4.w;
        #pragma unroll
        for (int o = 32; o > 0; o >>= 1) p += __shfl_xor(p, o, 64);
        p += bet;
        if (j == i0 + r) p = -1e30f;
        if (lane == jj) sv[r] = p;
      }
    }
    // store + per-wave softmax partials (lanes 0..31 hold values)
    float lmax = -1e30f;
    if (lane < 32){
      #pragma unroll
      for (int r = 0; r < 4; ++r){
        A.s2[(size_t)(i0+r)*kN + jbase + lane] = sv[r];
        lmax = fmaxf(lmax, sv[r]);
      }
    }
    float m = lmax;
    #pragma unroll
    for (int o = 32; o > 0; o >>= 1) m = fmaxf(m, __shfl_xor(m, o, 64));
    float z = 0.f;
    if (lane < 32){
      #pragma unroll
      for (int r = 0; r < 4; ++r) z += expf(sv[r] - m);
    }
    #pragma unroll
    for (int o = 32; o > 0; o >>= 1) z += __shfl_xor(z, o, 64);
    if (lane == 0){
      int pb = q*4 + w;
      A.maxp[pb] = m; A.zp[pb] = z;
    }
  }
}

// ---------- S4: [0,128) H1gemm->Hc | [128,192) h3->Hc | [192,200) h4 | 200 mz+zero gsum ----------
__global__ __launch_bounds__(256) void k_s4(Args A)
{
  __shared__ __align__(16) char SM[18432];
  int it = blockIdx.x, tid = threadIdx.x;
  if (it < 128){
    GS32 sg{A.wadj, A.Wh1, A.Hc, 512, 256, 320, 512, 1};
    gemm32_body(sg, it & 15, it >> 4, tid, (float*)SM, (float*)(SM + 9216));
  } else if (it < 192){
    int d = it - 128;
    int lane = tid & 63, wv = tid >> 6;
    float v0 = A.tfm[(size_t)(2*tid)*kHD + d];
    float v1 = A.tfm[(size_t)(2*tid+1)*kHD + d];
    float s = v0 + v1;
    float x = s;
    #pragma unroll
    for (int off = 1; off < 64; off <<= 1){
      float y = __shfl_up(x, off, 64);
      if (lane >= off) x += y;
    }
    float* wsum = (float*)SM;
    if (lane == 63) wsum[wv] = x;
    __syncthreads();
    float base = 0.f;
    for (int k = 0; k < wv; ++k) base += wsum[k];
    float excl = base + x - s;
    A.Hc[(size_t)(2*tid)*320 + 256 + d]   = (excl + v0) / (float)(2*tid + 1);
    A.Hc[(size_t)(2*tid+1)*320 + 256 + d] = (excl + s)  / (float)(2*tid + 2);
  } else if (it < 200){
    float* sm = (float*)SM;
    int d = tid & 63, sub = tid >> 6;
    int r0 = (it-192)*64 + sub*16;
    float s = 0.f;
    #pragma unroll
    for (int e = 0; e < 16; ++e) s += A.cfm[(size_t)(r0+e)*kHD + d];
    sm[sub*64 + d] = s;
    __syncthreads();
    if (tid < 64)
      atomicAdd(&A.H4v[tid], sm[tid] + sm[64+tid] + sm[128+tid] + sm[192+tid]);
  } else {
    float* red = (float*)SM;
    float m = -1e30f;
    #pragma unroll
    for (int r = 0; r < 8; ++r) m = fmaxf(m, A.maxp[tid + 256*r]);
    m = blk_red(m, red, true);
    float z = 0.f;
    #pragma unroll
    for (int r = 0; r < 8; ++r) z += A.zp[tid + 256*r] * expf(A.maxp[tid + 256*r] - m);
    z = blk_red(z, red, false);
    if (tid == 0){ A.MZ[0] = m; A.MZ[1] = z; }
    A.gsum[tid] = 0.f;
  }
}

// ---------- S5: [0,1024) gpart | [1024,1152) out3 (Hc @ Wcomb^T) ----------
__global__ __launch_bounds__(256) void k_s5(Args A)
{
  __shared__ __align__(16) char SM[18432];
  int it = blockIdx.x, tid = threadIdx.x;
  if (it < 1024){
    float* wt = (float*)SM;             // [16][16]
    int i0 = (it & 31) * 16, j0 = (it >> 5) * 16;
    float M = A.MZ[0], invZ = 1.0f / A.MZ[1];
    {
      int r = tid >> 4, c = tid & 15;
      wt[r*16 + c] = expf(A.s2[(size_t)(i0+r)*kN + (j0+c)] - M) * invZ;
    }
    float b1v = A.cb1f[tid];
    float aib[16];
    #pragma unroll
    for (int r = 0; r < 16; ++r) aib[r] = A.Am[(size_t)(i0+r)*kHID + tid] + b1v;
    __syncthreads();
    float acc = 0.f;
    for (int j = 0; j < 16; ++j){
      float bj = A.Bm[(size_t)(j0+j)*kHID + tid];
      #pragma unroll
      for (int r = 0; r < 16; ++r)
        acc += wt[r*16 + j] * fmaxf(aib[r] + bj, 0.f);
    }
    atomicAdd(&A.gsum[tid], acc);
  } else {
    int q = it - 1024;
    GS32 sg{A.Hc, A.Wcomb, A.out3, 320, 320, 256, 320, 0};
    gemm32_body(sg, q & 15, q >> 4, tid, (float*)SM, (float*)(SM + 9216));
  }
}

// ---------- S6: final ----------
__global__ __launch_bounds__(256) void k_s6(Args A)
{
  __shared__ float gs[kHID];
  __shared__ float part[kHD][4];
  __shared__ float h2s[kHD];
  __shared__ float cc2s[kOUT];
  int b = blockIdx.x, tid = threadIdx.x;
  bool f32 = (*A.flag != 0);
  gs[tid] = A.gsum[tid];
  __syncthreads();
  {
    int dd = tid >> 2, q = tid & 3;
    float a = 0.f;
    for (int kk = 0; kk < 64; ++kk){
      int k = q*64 + kk;
      a += gs[k] * A.cw2f[(size_t)dd*kHID + k];
    }
    part[dd][q] = a;
  }
  __syncthreads();
  if (tid < kHD)
    h2s[tid] = A.cb2f[tid] + part[tid][0] + part[tid][1] + part[tid][2] + part[tid][3];
  __syncthreads();
  {
    float a = 0.f;
    const float* om = A.OM + (size_t)tid*64;
    for (int d = 0; d < kHD; d += 4){
      float4 o4 = *(const float4*)(om + d);
      a += o4.x*h2s[d] + o4.y*h2s[d+1] + o4.z*h2s[d+2] + o4.w*h2s[d+3];
    }
    cc2s[tid] = a;
  }
  __syncthreads();
  int row = b*4 + (tid >> 6), lane = tid & 63;
  float h4r = (row < kHD) ? A.H4v[row] : 0.f;
  float4 v  = *(const float4*)(A.out3 + (size_t)row*kOUT + lane*4);
  float4 c2 = *(const float4*)(&cc2s[lane*4]);
  float4 o4 = *(const float4*)(A.ow4 + lane*4);
  float4 pb = *(const float4*)(A.opbf + lane*4);
  v.x += c2.x + h4r*o4.x + pb.x;
  v.y += c2.y + h4r*o4.y + pb.y;
  v.z += c2.z + h4r*o4.z + pb.z;
  v.w += c2.w + h4r*o4.w + pb.w;
  float s = v.x + v.y + v.z + v.w;
  #pragma unroll
  for (int o = 32; o > 0; o >>= 1) s += __shfl_xor(s, o, 64);
  float mu = s * (1.0f/kOUT);
  float dx = v.x-mu, dy = v.y-mu, dz = v.z-mu, dw = v.w-mu;
  float ss = dx*dx + dy*dy + dz*dz + dw*dw;
  #pragma unroll
  for (int o = 32; o > 0; o >>= 1) ss += __shfl_xor(ss, o, 64);
  float rs = rsqrtf(ss * (1.0f/kOUT) + 1e-5f);
  float4 g  = *(const float4*)(A.lngf + lane*4);
  float4 be = *(const float4*)(A.lnbf + lane*4);
  float y0 = dx*rs*g.x + be.x, y1 = dy*rs*g.y + be.y;
  float y2 = dz*rs*g.z + be.z, y3 = dw*rs*g.w + be.w;
  y0 = (y0 > 0.f) ? y0 : expm1f(y0);
  y1 = (y1 > 0.f) ? y1 : expm1f(y1);
  y2 = (y2 > 0.f) ? y2 : expm1f(y2);
  y3 = (y3 > 0.f) ? y3 : expm1f(y3);
  if (f32){
    *(float4*)((float*)A.out + (size_t)row*kOUT + lane*4) = make_float4(y0,y1,y2,y3);
  } else {
    ushort4 u; u.x = f2us(y0); u.y = f2us(y1); u.z = f2us(y2); u.w = f2us(y3);
    ((ushort4*)A.out)[(size_t)row*64 + lane] = u;
  }
}

extern "C" void kernel_launch(void* const* d_in, const int* in_sizes, int n_in,
                              void* d_out, int out_size, void* d_ws, size_t ws_size,
                              hipStream_t stream)
{
  const void* V     = d_in[0];
  const int*  adj   = (const int*)d_in[1];
  const void* prev  = d_in[2];
  const void* W1    = d_in[3];
  // d_in[4] = sa0 : dead (row-shift invariant softmax)
  const void* sa1   = d_in[5];
  const void* ce_w1 = d_in[6];
  const void* ce_b1 = d_in[7];
  const void* ce_w2 = d_in[8];
  const void* ce_b2 = d_in[9];
  const void* ca0   = d_in[10];
  const void* ca1   = d_in[11];
  const void* te_w1 = d_in[12];
  const void* te_b1 = d_in[13];
  const void* te_w2 = d_in[14];
  const void* te_b2 = d_in[15];
  // d_in[16,17] = ta0,ta1 : dead
  const void* pe_w1 = d_in[18];
  const void* pe_b1 = d_in[19];
  const void* pe_w2 = d_in[20];
  const void* pe_b2 = d_in[21];
  // d_in[22,23] = pa0,pa1 : dead
  const void* W2    = d_in[24];
  const void* op_w  = d_in[25];
  const void* op_b  = d_in[26];
  const void* ln_g  = d_in[27];
  const void* ln_b  = d_in[28];

  // ---- workspace layout (floats) ----
  float* ws  = (float*)d_ws;
  int*  flag = (int*)ws;               // 16 floats reserved
  float* p   = ws + 16;
  float* Vf   = p; p += 131072;
  float* prevf= p; p += 131072;
  float* W1f  = p; p += 65536;
  float* sa1f = p; p += 256;
  float* cw1f = p; p += 131072;
  float* cb1f = p; p += 256;
  float* cw2f = p; p += 16384;
  float* cb2f = p; p += 64;
  float* ca0f = p; p += 64;
  float* ca1f = p; p += 64;
  float* tw1f = p; p += 131072;
  float* tb1f = p; p += 256;
  float* tw2f = p; p += 16384;
  float* tb2f = p; p += 64;
  float* pw1f = p; p += 196608;
  float* pb1f = p; p += 256;
  float* pw2f = p; p += 16384;
  float* pb2f = p; p += 64;
  float* W2f  = p; p += 98560;
  float* opwf = p; p += 65536;
  float* opbf = p; p += 256;
  float* lngf = p; p += 256;
  float* lnbf = p; p += 256;
  float* tw2t = p; p += 16384;
  float* pw2t = p; p += 16384;
  float* Wcomb= p; p += 81920;
  float* OM   = p; p += 16384;
  float* ow4  = p; p += 256;
  float* Wh1      = p; p += 131072;
  float* e1v      = p; p += 512;
  float* wadj     = p; p += 262144;
  float* Hc       = p; p += 163840;
  float* Am       = p; p += 131072;
  float* Bm       = p; p += 131072;
  float* uvec     = p; p += 256;
  float* beta     = p; p += 16;
  float* s2       = p; p += 262144;
  float* maxp     = p; p += 4096;
  float* zpart    = p; p += 4096;
  float* MZ       = p; p += 16;
  float* gsum     = p; p += 256;
  float* htp0     = p; p += 131072;
  float* htp1     = p; p += 131072;
  float* hpp0     = p; p += 131072;
  float* hpp1     = p; p += 131072;
  float* hpp2     = p; p += 131072;
  float* hidden_t = p; p += 131072;
  float* hidden_p = p; p += 131072;
  float* tfm      = p; p += 32768;
  float* cfm      = p; p += 32768;
  float* H4v      = p; p += 64;
  float* Xp       = p; p += 393216;
  float* out3     = p; p += 131072;

  // ---- args bundle ----
  Args A;
  A.Vraw = (const unsigned int*)V; A.adj = adj;
  A.flag = flag; A.out = d_out;
  A.rca0 = ca0; A.rca1 = ca1; A.rcw2 = ce_w2; A.rcb2 = ce_b2; A.rtw2 = te_w2; A.rpw2 = pe_w2;
  A.Vf=Vf; A.prevf=prevf; A.W1f=W1f; A.sa1f=sa1f; A.cw1f=cw1f; A.cb1f=cb1f;
  A.cw2f=cw2f; A.cb2f=cb2f; A.ca0f=ca0f; A.ca1f=ca1f;
  A.tw1f=tw1f; A.tb1f=tb1f; A.tw2f=tw2f; A.tb2f=tb2f;
  A.pw1f=pw1f; A.pb1f=pb1f; A.pw2f=pw2f; A.pb2f=pb2f;
  A.W2f=W2f; A.opwf=opwf; A.opbf=opbf; A.lngf=lngf; A.lnbf=lnbf;
  A.tw2t=tw2t; A.pw2t=pw2t; A.Wcomb=Wcomb; A.OM=OM; A.ow4=ow4;
  A.Wh1=Wh1; A.e1v=e1v; A.wadj=wadj; A.Hc=Hc;
  A.Am=Am; A.Bm=Bm; A.uvec=uvec; A.beta=beta;
  A.s2=s2; A.maxp=maxp; A.zp=zpart; A.MZ=MZ; A.gsum=gsum;
  A.htp0=htp0; A.htp1=htp1; A.hpp0=hpp0; A.hpp1=hpp1; A.hpp2=hpp2;
  A.hidden_t=hidden_t; A.hidden_p=hidden_p;
  A.tfm=tfm; A.cfm=cfm; A.H4v=H4v; A.Xp=Xp; A.out3=out3;

  {
    const void* srcs[kNConv] = {V, prev, W1, sa1, ce_w1, ce_b1, ce_w2, ce_b2, ca0, ca1,
                                te_w1, te_b1, te_w2, te_b2, pe_w1, pe_b1, pe_w2, pe_b2,
                                W2, op_w, op_b, ln_g, ln_b};
    float* dsts[kNConv] = {Vf, prevf, W1f, sa1f, cw1f, cb1f, cw2f, cb2f, ca0f, ca1f,
                           tw1f, tb1f, tw2f, tb2f, pw1f, pb1f, pw2f, pb2f,
                           W2f, opwf, opbf, lngf, lnbf};
    int ns[kNConv] = {131072, 131072, 65536, 256, 131072, 256, 16384, 64, 64, 64,
                      131072, 256, 16384, 64, 196608, 256, 16384, 64,
                      98560, 65536, 256, 256, 256};
    for (int s = 0; s < kNConv; ++s){ A.ca.src[s] = srcs[s]; A.ca.dst[s] = dsts[s]; A.ca.n[s] = ns[s]; }
  }
  // gemmA: 8 uniform K=256 segments (R7 structure; partials summed by redH)
  A.gs[0] = {Vf,       W1f,        Wh1,  256, 256, 256, 256};
  A.gs[1] = {Vf,       cw1f,       Am,   256, 512, 256, 256};
  A.gs[2] = {Vf,       cw1f + 256, Bm,   256, 512, 256, 256};
  A.gs[3] = {Vf,       tw1f,       htp0, 256, 512, 256, 256};
  A.gs[4] = {prevf,    tw1f + 256, htp1, 256, 512, 256, 256};
  A.gs[5] = {Xp,       pw1f,       hpp0, 768, 768, 256, 256};
  A.gs[6] = {Xp + 256, pw1f + 256, hpp1, 768, 768, 256, 256};
  A.gs[7] = {Xp + 512, pw1f + 512, hpp2, 768, 768, 256, 256};

  // ---- 7-launch chain ----
  k_s0<<<771,  256, 0, stream>>>(A);
  k_s1<<<353,  256, 0, stream>>>(A);
  k_s2<<<640,  256, 0, stream>>>(A);
  k_s3<<<576,  256, 0, stream>>>(A);
  k_s4<<<201,  256, 0, stream>>>(A);
  k_s5<<<1152, 256, 0, stream>>>(A);
  k_s6<<<128,  256, 0, stream>>>(A);
}

// Round 12
// 235.486 us; speedup vs baseline: 1.1633x; 1.0813x over previous
//
#include <hip/hip_runtime.h>

typedef unsigned short u16;

constexpr int kN   = 512;
constexpr int kIN  = 256;
constexpr int kHID = 256;
constexpr int kHD  = 64;
constexpr int kOUT = 256;

// ---------- bf16 helpers ----------
__device__ __forceinline__ float us2f(u16 u){
  union { unsigned int i; float f; } c; c.i = ((unsigned int)u) << 16; return c.f;
}
__device__ __forceinline__ u16 f2us(float f){
  union { float f; unsigned int i; } c; c.f = f;
  unsigned int r = c.i + 0x7fff + ((c.i >> 16) & 1);
  return (u16)(r >> 16);
}
__device__ __forceinline__ float ldraw(const void* p, size_t i, bool f32){
  return f32 ? ((const float*)p)[i] : us2f(((const u16*)p)[i]);
}

// ---------- per-block dtype probe (reads first 16KB of V) ----------
__device__ bool probe_is_f32(const unsigned int* __restrict__ V){
  __shared__ int cnt;
  if (threadIdx.x == 0) cnt = 0;
  __syncthreads();
  int c = 0;
  for (int k = threadIdx.x; k < 4096; k += 256){
    float x = us2f((u16)(V[k] & 0xffffu));
    if (!(fabsf(x) <= 32.0f)) c++;
  }
  atomicAdd(&cnt, c);
  __syncthreads();
  return cnt > 64;
}

// ---------- block reduction (256 threads) ----------
__device__ __forceinline__ float blk_red(float v, float* tmp, bool isMax){
  int lane = threadIdx.x & 63, wv = threadIdx.x >> 6;
  #pragma unroll
  for (int o = 32; o > 0; o >>= 1){
    float t = __shfl_down(v, o, 64);
    v = isMax ? fmaxf(v, t) : (v + t);
  }
  __syncthreads();
  if (lane == 0) tmp[wv] = v;
  __syncthreads();
  float r = tmp[0];
  for (int i = 1; i < 4; ++i) r = isMax ? fmaxf(r, tmp[i]) : (r + tmp[i]);
  return r;
}

constexpr int kNConv = 23;
struct ConvArgs { const void* src[kNConv]; float* dst[kNConv]; int n[kNConv]; };
struct GSeg2 { const float* X; const float* W; float* C; int ldx, ldw, ldc, K; };
struct GS32 { const float* X; const float* W; float* C; int ldx, ldw, ldc, K; int bkn; };

struct Args {
  const unsigned int* Vraw;
  const int* adj;
  int* flag; void* out;
  const void *rca0,*rca1,*rcw2,*rcb2,*rtw2,*rpw2;
  float *Vf,*prevf,*W1f,*sa1f,*cw1f,*cb1f,*cw2f,*cb2f,*ca0f,*ca1f;
  float *tw1f,*tb1f,*tw2f,*tb2f,*pw1f,*pb1f,*pw2f,*pb2f;
  float *W2f,*opwf,*opbf,*lngf,*lnbf;
  float *tw2t,*pw2t,*Wcomb,*OM,*ow4;
  float *Wh1,*e1v,*wadj,*Hc,*Am,*Bm,*uvec,*beta;
  float *s2,*maxp,*zp,*MZ,*gsum;
  float *htp0,*htp1,*hpp0,*hpp1,*hpp2,*hidden_t,*hidden_p;
  float *tfm,*cfm,*H4v,*Xp,*out3;
  ConvArgs ca;
  GSeg2 gs[8];
};

// ================== GEMM-32 body: 32x32 tile, BK=32, 2x2 micro, dbuf ==================
__device__ __forceinline__ void gemm32_body(const GS32 sg, int tm, int tn, int tid,
                                            float* Xs, float* Ws)
{
  const int i0 = tm << 5, n0 = tn << 5;
  const int xrow = tid >> 3;
  const int xk = (tid & 7) << 2;
  const int rg = (tid >> 4) << 1;
  const int cg = (tid & 15) << 1;
  const float* Xb = sg.X + (size_t)i0 * sg.ldx;
  const float* Wb = sg.bkn ? (sg.W + n0) : (sg.W + (size_t)n0 * sg.ldw);
  float4 xr, wr;
  auto loadT = [&](int kt){
    xr = *(const float4*)(Xb + (size_t)xrow * sg.ldx + kt + xk);
    if (sg.bkn) wr = *(const float4*)(Wb + (size_t)(kt + xrow) * sg.ldw + xk);
    else        wr = *(const float4*)(Wb + (size_t)xrow * sg.ldw + kt + xk);
  };
  auto writeT = [&](int bu){
    float* xs = Xs + bu*1152;
    xs[(xk+0)*36 + xrow] = xr.x; xs[(xk+1)*36 + xrow] = xr.y;
    xs[(xk+2)*36 + xrow] = xr.z; xs[(xk+3)*36 + xrow] = xr.w;
    float* wsp = Ws + bu*1152;
    if (sg.bkn){
      wsp[xrow*36 + xk+0] = wr.x; wsp[xrow*36 + xk+1] = wr.y;
      wsp[xrow*36 + xk+2] = wr.z; wsp[xrow*36 + xk+3] = wr.w;
    } else {
      wsp[(xk+0)*36 + xrow] = wr.x; wsp[(xk+1)*36 + xrow] = wr.y;
      wsp[(xk+2)*36 + xrow] = wr.z; wsp[(xk+3)*36 + xrow] = wr.w;
    }
  };
  loadT(0); writeT(0); __syncthreads();
  float a00=0,a01=0,a10=0,a11=0;
  const int nkt = sg.K >> 5;
  for (int t = 0; t < nkt; ++t){
    if (t+1 < nkt) loadT((t+1) << 5);
    const float* xs = Xs + (t&1)*1152;
    const float* wsp = Ws + (t&1)*1152;
    #pragma unroll
    for (int kk = 0; kk < 32; ++kk){
      float2 av = *(const float2*)&xs[kk*36 + rg];
      float2 bv = *(const float2*)&wsp[kk*36 + cg];
      a00 += av.x*bv.x; a01 += av.x*bv.y;
      a10 += av.y*bv.x; a11 += av.y*bv.y;
    }
    if (t+1 < nkt) writeT((t+1)&1);
    __syncthreads();
  }
  float* cp = sg.C + (size_t)(i0+rg)*sg.ldc + n0 + cg;
  *(float2*)cp = make_float2(a00, a01);
  *(float2*)(cp + sg.ldc) = make_float2(a10, a11);
}

// ================== GEMM A body: 64x64 tile, BK=32, 4x4 micro, dbuf ==================
__device__ void body_gemmA(const Args& A, int it, int tid, char* SM)
{
  float (*Xs)[32][68] = (float (*)[32][68])SM;
  float (*Ws)[32][68] = (float (*)[32][68])(SM + 17408);
  int seg = it >> 5, x = it & 31;
  const GSeg2 sg = A.gs[seg];
  const int tm = x & 7, tn = x >> 3;
  const int i0 = tm << 6, n0 = tn << 6;

  const int xrow = tid >> 3;
  const int xk   = (tid & 7) << 2;
  const int rg = (tid >> 4) << 2;
  const int cg = (tid & 15) << 2;

  const float* Xb = sg.X + (size_t)i0 * sg.ldx;
  const float* Wb = sg.W + (size_t)n0 * sg.ldw;

  float4 xr0, xr1, wr0, wr1;
  auto loadT = [&](int kt){
    xr0 = *(const float4*)(Xb + (size_t)xrow * sg.ldx + kt + xk);
    xr1 = *(const float4*)(Xb + (size_t)(xrow+32) * sg.ldx + kt + xk);
    wr0 = *(const float4*)(Wb + (size_t)xrow * sg.ldw + kt + xk);
    wr1 = *(const float4*)(Wb + (size_t)(xrow+32) * sg.ldw + kt + xk);
  };
  auto writeT = [&](int bu){
    Xs[bu][xk+0][xrow] = xr0.x;  Xs[bu][xk+1][xrow] = xr0.y;
    Xs[bu][xk+2][xrow] = xr0.z;  Xs[bu][xk+3][xrow] = xr0.w;
    Xs[bu][xk+0][xrow+32] = xr1.x;  Xs[bu][xk+1][xrow+32] = xr1.y;
    Xs[bu][xk+2][xrow+32] = xr1.z;  Xs[bu][xk+3][xrow+32] = xr1.w;
    Ws[bu][xk+0][xrow]    = wr0.x; Ws[bu][xk+1][xrow]    = wr0.y;
    Ws[bu][xk+2][xrow]    = wr0.z; Ws[bu][xk+3][xrow]    = wr0.w;
    Ws[bu][xk+0][xrow+32] = wr1.x; Ws[bu][xk+1][xrow+32] = wr1.y;
    Ws[bu][xk+2][xrow+32] = wr1.z; Ws[bu][xk+3][xrow+32] = wr1.w;
  };

  loadT(0); writeT(0); __syncthreads();

  float acc[4][4] = {};
  const int nkt = sg.K >> 5;
  for (int t = 0; t < nkt; ++t){
    if (t + 1 < nkt) loadT((t + 1) << 5);
    const int bu = t & 1;
    #pragma unroll
    for (int kk = 0; kk < 32; ++kk){
      const float4 av = *(const float4*)&Xs[bu][kk][rg];
      const float4 bv = *(const float4*)&Ws[bu][kk][cg];
      acc[0][0]+=av.x*bv.x; acc[0][1]+=av.x*bv.y; acc[0][2]+=av.x*bv.z; acc[0][3]+=av.x*bv.w;
      acc[1][0]+=av.y*bv.x; acc[1][1]+=av.y*bv.y; acc[1][2]+=av.y*bv.z; acc[1][3]+=av.y*bv.w;
      acc[2][0]+=av.z*bv.x; acc[2][1]+=av.z*bv.y; acc[2][2]+=av.z*bv.z; acc[2][3]+=av.z*bv.w;
      acc[3][0]+=av.w*bv.x; acc[3][1]+=av.w*bv.y; acc[3][2]+=av.w*bv.z; acc[3][3]+=av.w*bv.w;
    }
    if (t + 1 < nkt) writeT((t + 1) & 1);
    __syncthreads();
  }

  #pragma unroll
  for (int ri = 0; ri < 4; ++ri)
    *(float4*)(sg.C + (size_t)(i0 + rg + ri) * sg.ldc + (n0 + cg)) =
      make_float4(acc[ri][0], acc[ri][1], acc[ri][2], acc[ri][3]);

  // seg 0 = Wh1: fused e1 partial (e1[j] = Wh1[j,:].sa1)
  if (seg == 0){
    int cb = n0 + cg;
    float s0 = A.sa1f[cb], s1 = A.sa1f[cb+1], s2v = A.sa1f[cb+2], s3 = A.sa1f[cb+3];
    #pragma unroll
    for (int ri = 0; ri < 4; ++ri){
      float v = acc[ri][0]*s0 + acc[ri][1]*s1 + acc[ri][2]*s2v + acc[ri][3]*s3;
      v += __shfl_xor(v, 1, 16);
      v += __shfl_xor(v, 2, 16);
      v += __shfl_xor(v, 4, 16);
      v += __shfl_xor(v, 8, 16);
      if ((tid & 15) == 0) atomicAdd(&A.e1v[i0 + rg + ri], v);
    }
  }
}

// ---------- S0: [0,256) convert | [256,768) packsel(Xp) | 768 ub+zeroH4v | 769,770 transposes ----------
__global__ __launch_bounds__(256) void k_s0(Args A)
{
  __shared__ __align__(16) char SM[16896];
  int it = blockIdx.x, tid = threadIdx.x;
  bool f32 = probe_is_f32(A.Vraw);
  if (it < 256){
    if (it == 0){
      if (tid == 0) *A.flag = f32 ? 1 : 0;
      A.e1v[tid] = 0.f; A.e1v[tid + 256] = 0.f;
    }
    int t = it*256 + tid;
    for (int s = 0; s < kNConv; ++s){
      int n4 = A.ca.n[s] >> 2;
      float4* d = (float4*)A.ca.dst[s];
      if (f32){
        const float4* sf = (const float4*)A.ca.src[s];
        for (int i = t; i < n4; i += 65536) d[i] = sf[i];
      } else {
        const ushort4* sb = (const ushort4*)A.ca.src[s];
        for (int i = t; i < n4; i += 65536){
          ushort4 u = sb[i];
          d[i] = make_float4(us2f(u.x), us2f(u.y), us2f(u.z), us2f(u.w));
        }
      }
    }
  } else if (it < 768){
    unsigned long long* msk = (unsigned long long*)SM;
    int* sj = (int*)(SM + 64);
    int i = it - 256;
    int w = tid >> 6, lane = tid & 63;
    unsigned long long m0 = __ballot(A.adj[(size_t)i*kN + tid] != 0);
    unsigned long long m1 = __ballot(A.adj[(size_t)i*kN + 256 + tid] != 0);
    if (lane == 0){ msk[w] = m0; msk[4 + w] = m1; }
    __syncthreads();
    if (tid == 0){
      int j0 = -1, j1 = -1;
      for (int c = 0; c < 8 && j1 < 0; ++c){
        unsigned long long m = msk[c];
        while (m && j1 < 0){
          int bb = __builtin_ctzll(m);
          int j = c*64 + bb;
          if (j0 < 0) j0 = j; else j1 = j;
          m &= m - 1;
        }
      }
      if (j1 < 0) j0 = -1;
      sj[0] = j0; sj[1] = j1;
    }
    __syncthreads();
    int j0 = sj[0], j1 = sj[1];
    A.Xp[(size_t)i*768 + tid]       = ldraw(A.Vraw, (size_t)i*kIN + tid, f32);
    A.Xp[(size_t)i*768 + 256 + tid] = (j0 >= 0) ? ldraw(A.Vraw, (size_t)j0*kIN + tid, f32) : 0.f;
    A.Xp[(size_t)i*768 + 512 + tid] = (j1 >= 0) ? ldraw(A.Vraw, (size_t)j1*kIN + tid, f32) : 0.f;
  } else if (it == 768){
    float* st = (float*)SM;
    if (tid < 64){ st[tid] = ldraw(A.rca0, tid, f32) + ldraw(A.rca1, tid, f32); A.H4v[tid] = 0.f; }
    __syncthreads();
    float a = 0.f;
    for (int d = 0; d < kHD; ++d) a += ldraw(A.rcw2, (size_t)d*kHID + tid, f32) * st[d];
    A.uvec[tid] = a;
    if (tid == 0){
      float b = 0.f;
      for (int d = 0; d < kHD; ++d) b += ldraw(A.rcb2, d, f32) * st[d];
      *A.beta = b;
    }
  } else {
    const void* src = (it == 769) ? A.rtw2 : A.rpw2;
    float* dst = (it == 769) ? A.tw2t : A.pw2t;
    float* st = (float*)SM;   // 64*65 floats
    for (int ch = 0; ch < 4; ++ch){
      __syncthreads();
      #pragma unroll
      for (int e = 0; e < 16; ++e){
        int lin = e*256 + tid, r = lin >> 6, c = lin & 63;
        st[r*65 + c] = ldraw(src, (size_t)r*256 + ch*64 + c, f32);
      }
      __syncthreads();
      #pragma unroll
      for (int e = 0; e < 16; ++e){
        int lin = e*256 + tid, kc = lin >> 6, dd = lin & 63;
        dst[(size_t)(ch*64 + kc)*64 + dd] = st[dd*65 + kc];
      }
    }
  }
}

// ---------- S1: [0,256) gemmA(+e1) | [256,336) Wcomb | [336,352) OM | 352 ow4 ----------
__global__ __launch_bounds__(256) void k_s1(Args A)
{
  __shared__ __align__(16) char SM[34816];
  int it = blockIdx.x, tid = threadIdx.x;
  if (it < 256){
    body_gemmA(A, it, tid, SM);
  } else if (it < 336){
    int q = it - 256, tm = q & 7, tn = q >> 3;
    const float* Wsrc = A.W2f + ((tn < 8) ? 0 : 64);
    GS32 sg{A.opwf, Wsrc, A.Wcomb, 256, 385, 320, 256, 1};
    gemm32_body(sg, tm, tn, tid, (float*)SM, (float*)(SM + 9216));
  } else if (it < 352){
    int q = it - 336;
    GS32 sg{A.opwf, A.W2f + 256, A.OM, 256, 385, 64, 256, 1};
    gemm32_body(sg, q & 7, q >> 3, tid, (float*)SM, (float*)(SM + 9216));
  } else {
    float* st = (float*)SM;
    st[tid] = A.W2f[(size_t)tid*385 + 384];
    __syncthreads();
    float a = 0.f;
    const float* orow = A.opwf + (size_t)tid*256;
    for (int m = 0; m < 256; m += 4){
      float4 o4 = *(const float4*)(orow + m);
      a += o4.x*st[m] + o4.y*st[m+1] + o4.z*st[m+2] + o4.w*st[m+3];
    }
    A.ow4[tid] = a;
  }
}

// ---------- S2: [0,128) redH | [128,640) h1stats+wadj ----------
__global__ __launch_bounds__(256) void k_s2(Args A)
{
  __shared__ float SM2[8];
  int it = blockIdx.x, tid = threadIdx.x;
  if (it < 128){
    int f = it*256 + tid;
    int c4 = f & 63;
    {
      float4 a = ((const float4*)A.htp0)[f], bb = ((const float4*)A.htp1)[f];
      float4 bi = ((const float4*)A.tb1f)[c4];
      ((float4*)A.hidden_t)[f] = make_float4(
        fmaxf(a.x+bb.x+bi.x,0.f), fmaxf(a.y+bb.y+bi.y,0.f),
        fmaxf(a.z+bb.z+bi.z,0.f), fmaxf(a.w+bb.w+bi.w,0.f));
    }
    {
      float4 a = ((const float4*)A.hpp0)[f], bb = ((const float4*)A.hpp1)[f];
      float4 c = ((const float4*)A.hpp2)[f];
      float4 bi = ((const float4*)A.pb1f)[c4];
      ((float4*)A.hidden_p)[f] = make_float4(
        fmaxf(a.x+bb.x+c.x+bi.x,0.f), fmaxf(a.y+bb.y+c.y+bi.y,0.f),
        fmaxf(a.z+bb.z+c.z+bi.z,0.f), fmaxf(a.w+bb.w+c.w+bi.w,0.f));
    }
  } else {
    int i = it - 128;
    int m0 = A.adj[(size_t)i*kN + tid];
    int m1 = A.adj[(size_t)i*kN + tid + 256];
    float ea = A.e1v[tid], eb = A.e1v[tid+256];
    float v0 = m0 ? ea : -1e30f;
    float v1 = m1 ? eb : -1e30f;
    float m = blk_red(fmaxf(v0, v1), SM2, true);
    float z = blk_red((m0 ? expf(ea-m) : 0.f) + (m1 ? expf(eb-m) : 0.f), SM2, false);
    float iz = 1.0f / z;
    A.wadj[(size_t)i*kN + tid]       = m0 ? expf(ea - m) * iz : 0.f;
    A.wadj[(size_t)i*kN + tid + 256] = m1 ? expf(eb - m) * iz : 0.f;
  }
}

// ---------- S3: [0,64) gemmB(reg) | [64,320) s2 scores (32x32 GEMM-style tiles) ----------
__global__ __launch_bounds__(256) void k_s3(Args A)
{
  __shared__ __align__(16) float SM3[32*36*2 + 256 + 256 + 8];
  int it = blockIdx.x, tid = threadIdx.x;
  if (it < 64){
    int m = it >> 5, grp = it & 31;
    const float* X  = m ? A.hidden_p : A.hidden_t;
    const float* Wt = m ? A.pw2t : A.tw2t;
    const float* bi = m ? A.pb2f : A.tb2f;
    float* C = m ? A.cfm : A.tfm;
    int i0 = grp*16 + (tid >> 6)*4;
    int d = tid & 63;
    const float* x0 = X + (size_t)i0*256;
    const float* x1 = x0 + 256;
    const float* x2 = x0 + 512;
    const float* x3 = x0 + 768;
    float a0=0.f, a1=0.f, a2=0.f, a3=0.f;
    for (int k = 0; k < 256; k += 4){
      float w0 = Wt[(size_t)(k+0)*64 + d];
      float w1 = Wt[(size_t)(k+1)*64 + d];
      float w2 = Wt[(size_t)(k+2)*64 + d];
      float w3 = Wt[(size_t)(k+3)*64 + d];
      float4 f0 = *(const float4*)(x0 + k);
      float4 f1 = *(const float4*)(x1 + k);
      float4 f2 = *(const float4*)(x2 + k);
      float4 f3 = *(const float4*)(x3 + k);
      a0 += f0.x*w0 + f0.y*w1 + f0.z*w2 + f0.w*w3;
      a1 += f1.x*w0 + f1.y*w1 + f1.z*w2 + f1.w*w3;
      a2 += f2.x*w0 + f2.y*w1 + f2.z*w2 + f2.w*w3;
      a3 += f3.x*w0 + f3.y*w1 + f3.z*w2 + f3.w*w3;
    }
    float bd = bi[d];
    C[(size_t)(i0+0)*64 + d] = a0 + bd;
    C[(size_t)(i0+1)*64 + d] = a1 + bd;
    C[(size_t)(i0+2)*64 + d] = a2 + bd;
    C[(size_t)(i0+3)*64 + d] = a3 + bd;
  } else {
    // 32x32 (i,j) tile; LDS-staged k-chunks; per-lane VALU only (no shuffles in k-loop)
    float* As = SM3;                 // [32][36]  (k-major, b1 folded)
    float* Bs = As + 32*36;          // [32][36]
    float* Us = Bs + 32*36;          // [256]
    float* B1 = Us + 256;            // [256]
    float* red = B1 + 256;           // [8]
    int q = it - 64;                 // 0..255
    int i0 = (q & 15) * 32, j0 = (q >> 4) * 32;
    Us[tid] = A.uvec[tid];
    B1[tid] = A.cb1f[tid];
    const int xrow = tid >> 3;
    const int xk   = (tid & 7) << 2;
    const int rg = (tid >> 4) << 1;
    const int cg = (tid & 15) << 1;
    float acc[2][2] = {};
    for (int kt = 0; kt < 256; kt += 32){
      __syncthreads();
      float4 av = *(const float4*)(A.Am + (size_t)(i0+xrow)*kHID + kt + xk);
      float4 bv = *(const float4*)(A.Bm + (size_t)(j0+xrow)*kHID + kt + xk);
      As[(xk+0)*36 + xrow] = av.x + B1[kt+xk+0];
      As[(xk+1)*36 + xrow] = av.y + B1[kt+xk+1];
      As[(xk+2)*36 + xrow] = av.z + B1[kt+xk+2];
      As[(xk+3)*36 + xrow] = av.w + B1[kt+xk+3];
      Bs[(xk+0)*36 + xrow] = bv.x;
      Bs[(xk+1)*36 + xrow] = bv.y;
      Bs[(xk+2)*36 + xrow] = bv.z;
      Bs[(xk+3)*36 + xrow] = bv.w;
      __syncthreads();
      #pragma unroll
      for (int kk = 0; kk < 32; ++kk){
        float uk = Us[kt + kk];
        float2 a2 = *(const float2*)&As[kk*36 + rg];
        float2 b2 = *(const float2*)&Bs[kk*36 + cg];
        acc[0][0] += fmaxf(a2.x + b2.x, 0.f) * uk;
        acc[0][1] += fmaxf(a2.x + b2.y, 0.f) * uk;
        acc[1][0] += fmaxf(a2.y + b2.x, 0.f) * uk;
        acc[1][1] += fmaxf(a2.y + b2.y, 0.f) * uk;
      }
    }
    float bet = *A.beta;
    float sv[2][2];
    #pragma unroll
    for (int r = 0; r < 2; ++r){
      #pragma unroll
      for (int c = 0; c < 2; ++c){
        float vsc = acc[r][c] + bet;
        int i = i0 + rg + r, j = j0 + cg + c;
        if (i == j) vsc = -1e30f;
        sv[r][c] = vsc;
        A.s2[(size_t)i*kN + j] = vsc;
      }
    }
    __syncthreads();   // protect red[] reuse after k-loop LDS reads
    float m = blk_red(fmaxf(fmaxf(sv[0][0], sv[0][1]), fmaxf(sv[1][0], sv[1][1])), red, true);
    float z = expf(sv[0][0]-m) + expf(sv[0][1]-m) + expf(sv[1][0]-m) + expf(sv[1][1]-m);
    z = blk_red(z, red, false);
    if (tid == 0){ A.maxp[q] = m; A.zp[q] = z; }
  }
}

// ---------- S4: [0,128) H1gemm->Hc | [128,192) h3->Hc | [192,200) h4 | 200 mz+zero gsum ----------
__global__ __launch_bounds__(256) void k_s4(Args A)
{
  __shared__ __align__(16) char SM[18432];
  int it = blockIdx.x, tid = threadIdx.x;
  if (it < 128){
    GS32 sg{A.wadj, A.Wh1, A.Hc, 512, 256, 320, 512, 1};
    gemm32_body(sg, it & 15, it >> 4, tid, (float*)SM, (float*)(SM + 9216));
  } else if (it < 192){
    int d = it - 128;
    int lane = tid & 63, wv = tid >> 6;
    float v0 = A.tfm[(size_t)(2*tid)*kHD + d];
    float v1 = A.tfm[(size_t)(2*tid+1)*kHD + d];
    float s = v0 + v1;
    float x = s;
    #pragma unroll
    for (int off = 1; off < 64; off <<= 1){
      float y = __shfl_up(x, off, 64);
      if (lane >= off) x += y;
    }
    float* wsum = (float*)SM;
    if (lane == 63) wsum[wv] = x;
    __syncthreads();
    float base = 0.f;
    for (int k = 0; k < wv; ++k) base += wsum[k];
    float excl = base + x - s;
    A.Hc[(size_t)(2*tid)*320 + 256 + d]   = (excl + v0) / (float)(2*tid + 1);
    A.Hc[(size_t)(2*tid+1)*320 + 256 + d] = (excl + s)  / (float)(2*tid + 2);
  } else if (it < 200){
    float* sm = (float*)SM;
    int d = tid & 63, sub = tid >> 6;
    int r0 = (it-192)*64 + sub*16;
    float s = 0.f;
    #pragma unroll
    for (int e = 0; e < 16; ++e) s += A.cfm[(size_t)(r0+e)*kHD + d];
    sm[sub*64 + d] = s;
    __syncthreads();
    if (tid < 64)
      atomicAdd(&A.H4v[tid], sm[tid] + sm[64+tid] + sm[128+tid] + sm[192+tid]);
  } else {
    float* red = (float*)SM;
    float m = blk_red(A.maxp[tid], red, true);   // 256 partials, one per thread
    float z = A.zp[tid] * expf(A.maxp[tid] - m);
    z = blk_red(z, red, false);
    if (tid == 0){ A.MZ[0] = m; A.MZ[1] = z; }
    A.gsum[tid] = 0.f;
  }
}

// ---------- S5: [0,1024) gpart | [1024,1152) out3 (Hc @ Wcomb^T) ----------
__global__ __launch_bounds__(256) void k_s5(Args A)
{
  __shared__ __align__(16) char SM[18432];
  int it = blockIdx.x, tid = threadIdx.x;
  if (it < 1024){
    float* wt = (float*)SM;             // [16][16]
    int i0 = (it & 31) * 16, j0 = (it >> 5) * 16;
    float M = A.MZ[0], invZ = 1.0f / A.MZ[1];
    {
      int r = tid >> 4, c = tid & 15;
      wt[r*16 + c] = expf(A.s2[(size_t)(i0+r)*kN + (j0+c)] - M) * invZ;
    }
    float b1v = A.cb1f[tid];
    float aib[16];
    #pragma unroll
    for (int r = 0; r < 16; ++r) aib[r] = A.Am[(size_t)(i0+r)*kHID + tid] + b1v;
    __syncthreads();
    float acc = 0.f;
    for (int j = 0; j < 16; ++j){
      float bj = A.Bm[(size_t)(j0+j)*kHID + tid];
      #pragma unroll
      for (int r = 0; r < 16; ++r)
        acc += wt[r*16 + j] * fmaxf(aib[r] + bj, 0.f);
    }
    atomicAdd(&A.gsum[tid], acc);
  } else {
    int q = it - 1024;
    GS32 sg{A.Hc, A.Wcomb, A.out3, 320, 320, 256, 320, 0};
    gemm32_body(sg, q & 15, q >> 4, tid, (float*)SM, (float*)(SM + 9216));
  }
}

// ---------- S6: final ----------
__global__ __launch_bounds__(256) void k_s6(Args A)
{
  __shared__ float gs[kHID];
  __shared__ float part[kHD][4];
  __shared__ float h2s[kHD];
  __shared__ float cc2s[kOUT];
  int b = blockIdx.x, tid = threadIdx.x;
  bool f32 = (*A.flag != 0);
  gs[tid] = A.gsum[tid];
  __syncthreads();
  {
    int dd = tid >> 2, q = tid & 3;
    float a = 0.f;
    for (int kk = 0; kk < 64; ++kk){
      int k = q*64 + kk;
      a += gs[k] * A.cw2f[(size_t)dd*kHID + k];
    }
    part[dd][q] = a;
  }
  __syncthreads();
  if (tid < kHD)
    h2s[tid] = A.cb2f[tid] + part[tid][0] + part[tid][1] + part[tid][2] + part[tid][3];
  __syncthreads();
  {
    float a = 0.f;
    const float* om = A.OM + (size_t)tid*64;
    for (int d = 0; d < kHD; d += 4){
      float4 o4 = *(const float4*)(om + d);
      a += o4.x*h2s[d] + o4.y*h2s[d+1] + o4.z*h2s[d+2] + o4.w*h2s[d+3];
    }
    cc2s[tid] = a;
  }
  __syncthreads();
  int row = b*4 + (tid >> 6), lane = tid & 63;
  float h4r = (row < kHD) ? A.H4v[row] : 0.f;
  float4 v  = *(const float4*)(A.out3 + (size_t)row*kOUT + lane*4);
  float4 c2 = *(const float4*)(&cc2s[lane*4]);
  float4 o4 = *(const float4*)(A.ow4 + lane*4);
  float4 pb = *(const float4*)(A.opbf + lane*4);
  v.x += c2.x + h4r*o4.x + pb.x;
  v.y += c2.y + h4r*o4.y + pb.y;
  v.z += c2.z + h4r*o4.z + pb.z;
  v.w += c2.w + h4r*o4.w + pb.w;
  float s = v.x + v.y + v.z + v.w;
  #pragma unroll
  for (int o = 32; o > 0; o >>= 1) s += __shfl_xor(s, o, 64);
  float mu = s * (1.0f/kOUT);
  float dx = v.x-mu, dy = v.y-mu, dz = v.z-mu, dw = v.w-mu;
  float ss = dx*dx + dy*dy + dz*dz + dw*dw;
  #pragma unroll
  for (int o = 32; o > 0; o >>= 1) ss += __shfl_xor(ss, o, 64);
  float rs = rsqrtf(ss * (1.0f/kOUT) + 1e-5f);
  float4 g  = *(const float4*)(A.lngf + lane*4);
  float4 be = *(const float4*)(A.lnbf + lane*4);
  float y0 = dx*rs*g.x + be.x, y1 = dy*rs*g.y + be.y;
  float y2 = dz*rs*g.z + be.z, y3 = dw*rs*g.w + be.w;
  y0 = (y0 > 0.f) ? y0 : expm1f(y0);
  y1 = (y1 > 0.f) ? y1 : expm1f(y1);
  y2 = (y2 > 0.f) ? y2 : expm1f(y2);
  y3 = (y3 > 0.f) ? y3 : expm1f(y3);
  if (f32){
    *(float4*)((float*)A.out + (size_t)row*kOUT + lane*4) = make_float4(y0,y1,y2,y3);
  } else {
    ushort4 u; u.x = f2us(y0); u.y = f2us(y1); u.z = f2us(y2); u.w = f2us(y3);
    ((ushort4*)A.out)[(size_t)row*64 + lane] = u;
  }
}

extern "C" void kernel_launch(void* const* d_in, const int* in_sizes, int n_in,
                              void* d_out, int out_size, void* d_ws, size_t ws_size,
                              hipStream_t stream)
{
  const void* V     = d_in[0];
  const int*  adj   = (const int*)d_in[1];
  const void* prev  = d_in[2];
  const void* W1    = d_in[3];
  // d_in[4] = sa0 : dead (row-shift invariant softmax)
  const void* sa1   = d_in[5];
  const void* ce_w1 = d_in[6];
  const void* ce_b1 = d_in[7];
  const void* ce_w2 = d_in[8];
  const void* ce_b2 = d_in[9];
  const void* ca0   = d_in[10];
  const void* ca1   = d_in[11];
  const void* te_w1 = d_in[12];
  const void* te_b1 = d_in[13];
  const void* te_w2 = d_in[14];
  const void* te_b2 = d_in[15];
  // d_in[16,17] = ta0,ta1 : dead
  const void* pe_w1 = d_in[18];
  const void* pe_b1 = d_in[19];
  const void* pe_w2 = d_in[20];
  const void* pe_b2 = d_in[21];
  // d_in[22,23] = pa0,pa1 : dead
  const void* W2    = d_in[24];
  const void* op_w  = d_in[25];
  const void* op_b  = d_in[26];
  const void* ln_g  = d_in[27];
  const void* ln_b  = d_in[28];

  // ---- workspace layout (floats) ----
  float* ws  = (float*)d_ws;
  int*  flag = (int*)ws;               // 16 floats reserved
  float* p   = ws + 16;
  float* Vf   = p; p += 131072;
  float* prevf= p; p += 131072;
  float* W1f  = p; p += 65536;
  float* sa1f = p; p += 256;
  float* cw1f = p; p += 131072;
  float* cb1f = p; p += 256;
  float* cw2f = p; p += 16384;
  float* cb2f = p; p += 64;
  float* ca0f = p; p += 64;
  float* ca1f = p; p += 64;
  float* tw1f = p; p += 131072;
  float* tb1f = p; p += 256;
  float* tw2f = p; p += 16384;
  float* tb2f = p; p += 64;
  float* pw1f = p; p += 196608;
  float* pb1f = p; p += 256;
  float* pw2f = p; p += 16384;
  float* pb2f = p; p += 64;
  float* W2f  = p; p += 98560;
  float* opwf = p; p += 65536;
  float* opbf = p; p += 256;
  float* lngf = p; p += 256;
  float* lnbf = p; p += 256;
  float* tw2t = p; p += 16384;
  float* pw2t = p; p += 16384;
  float* Wcomb= p; p += 81920;
  float* OM   = p; p += 16384;
  float* ow4  = p; p += 256;
  float* Wh1      = p; p += 131072;
  float* e1v      = p; p += 512;
  float* wadj     = p; p += 262144;
  float* Hc       = p; p += 163840;
  float* Am       = p; p += 131072;
  float* Bm       = p; p += 131072;
  float* uvec     = p; p += 256;
  float* beta     = p; p += 16;
  float* s2       = p; p += 262144;
  float* maxp     = p; p += 4096;
  float* zpart    = p; p += 4096;
  float* MZ       = p; p += 16;
  float* gsum     = p; p += 256;
  float* htp0     = p; p += 131072;
  float* htp1     = p; p += 131072;
  float* hpp0     = p; p += 131072;
  float* hpp1     = p; p += 131072;
  float* hpp2     = p; p += 131072;
  float* hidden_t = p; p += 131072;
  float* hidden_p = p; p += 131072;
  float* tfm      = p; p += 32768;
  float* cfm      = p; p += 32768;
  float* H4v      = p; p += 64;
  float* Xp       = p; p += 393216;
  float* out3     = p; p += 131072;

  // ---- args bundle ----
  Args A;
  A.Vraw = (const unsigned int*)V; A.adj = adj;
  A.flag = flag; A.out = d_out;
  A.rca0 = ca0; A.rca1 = ca1; A.rcw2 = ce_w2; A.rcb2 = ce_b2; A.rtw2 = te_w2; A.rpw2 = pe_w2;
  A.Vf=Vf; A.prevf=prevf; A.W1f=W1f; A.sa1f=sa1f; A.cw1f=cw1f; A.cb1f=cb1f;
  A.cw2f=cw2f; A.cb2f=cb2f; A.ca0f=ca0f; A.ca1f=ca1f;
  A.tw1f=tw1f; A.tb1f=tb1f; A.tw2f=tw2f; A.tb2f=tb2f;
  A.pw1f=pw1f; A.pb1f=pb1f; A.pw2f=pw2f; A.pb2f=pb2f;
  A.W2f=W2f; A.opwf=opwf; A.opbf=opbf; A.lngf=lngf; A.lnbf=lnbf;
  A.tw2t=tw2t; A.pw2t=pw2t; A.Wcomb=Wcomb; A.OM=OM; A.ow4=ow4;
  A.Wh1=Wh1; A.e1v=e1v; A.wadj=wadj; A.Hc=Hc;
  A.Am=Am; A.Bm=Bm; A.uvec=uvec; A.beta=beta;
  A.s2=s2; A.maxp=maxp; A.zp=zpart; A.MZ=MZ; A.gsum=gsum;
  A.htp0=htp0; A.htp1=htp1; A.hpp0=hpp0; A.hpp1=hpp1; A.hpp2=hpp2;
  A.hidden_t=hidden_t; A.hidden_p=hidden_p;
  A.tfm=tfm; A.cfm=cfm; A.H4v=H4v; A.Xp=Xp; A.out3=out3;

  {
    const void* srcs[kNConv] = {V, prev, W1, sa1, ce_w1, ce_b1, ce_w2, ce_b2, ca0, ca1,
                                te_w1, te_b1, te_w2, te_b2, pe_w1, pe_b1, pe_w2, pe_b2,
                                W2, op_w, op_b, ln_g, ln_b};
    float* dsts[kNConv] = {Vf, prevf, W1f, sa1f, cw1f, cb1f, cw2f, cb2f, ca0f, ca1f,
                           tw1f, tb1f, tw2f, tb2f, pw1f, pb1f, pw2f, pb2f,
                           W2f, opwf, opbf, lngf, lnbf};
    int ns[kNConv] = {131072, 131072, 65536, 256, 131072, 256, 16384, 64, 64, 64,
                      131072, 256, 16384, 64, 196608, 256, 16384, 64,
                      98560, 65536, 256, 256, 256};
    for (int s = 0; s < kNConv; ++s){ A.ca.src[s] = srcs[s]; A.ca.dst[s] = dsts[s]; A.ca.n[s] = ns[s]; }
  }
  // gemmA: 8 uniform K=256 segments (partials summed by redH)
  A.gs[0] = {Vf,       W1f,        Wh1,  256, 256, 256, 256};
  A.gs[1] = {Vf,       cw1f,       Am,   256, 512, 256, 256};
  A.gs[2] = {Vf,       cw1f + 256, Bm,   256, 512, 256, 256};
  A.gs[3] = {Vf,       tw1f,       htp0, 256, 512, 256, 256};
  A.gs[4] = {prevf,    tw1f + 256, htp1, 256, 512, 256, 256};
  A.gs[5] = {Xp,       pw1f,       hpp0, 768, 768, 256, 256};
  A.gs[6] = {Xp + 256, pw1f + 256, hpp1, 768, 768, 256, 256};
  A.gs[7] = {Xp + 512, pw1f + 512, hpp2, 768, 768, 256, 256};

  // ---- 7-launch chain ----
  k_s0<<<771,  256, 0, stream>>>(A);
  k_s1<<<353,  256, 0, stream>>>(A);
  k_s2<<<640,  256, 0, stream>>>(A);
  k_s3<<<320,  256, 0, stream>>>(A);
  k_s4<<<201,  256, 0, stream>>>(A);
  k_s5<<<1152, 256, 0, stream>>>(A);
  k_s6<<<128,  256, 0, stream>>>(A);
}